// Round 12
// baseline (396.881 us; speedup 1.0000x reference)
//
#include <hip/hip_runtime.h>
#include <hip/hip_bf16.h>
#include <cstddef>

#define NB 2
#define SEQ 2048
#define DIMX 4096
#define NH 16
#define NKV 4
#define HD 64
#define LATENT 1024
#define KVD 256
#define QKVN 1536
#define BS (NB*SEQ)
#define SP (SEQ+2)   // padded token rows per batch for conv2 input

typedef __attribute__((ext_vector_type(8))) short short8v;   // 8 bf16 = 4 VGPR
typedef __attribute__((ext_vector_type(4))) float f32x4;
typedef __attribute__((ext_vector_type(4))) unsigned short ushort4v;
typedef __attribute__((ext_vector_type(4))) unsigned int uint4v;

static __device__ __forceinline__ unsigned short f2bf(float f) {
    union { float f; unsigned u; } v; v.f = f;
    unsigned r = v.u + 0x7fffu + ((v.u >> 16) & 1u);
    return (unsigned short)(r >> 16);
}

static __device__ __forceinline__ unsigned cvt_pk_bf16(float lo, float hi) {
    unsigned r;
    asm("v_cvt_pk_bf16_f32 %0, %1, %2" : "=v"(r) : "v"(lo), "v"(hi));
    return r;
}

static __device__ __forceinline__ void gload_lds16(const unsigned short* g, unsigned short* l) {
    __builtin_amdgcn_global_load_lds((const __attribute__((address_space(1))) void*)g,
                                     (__attribute__((address_space(3))) void*)l, 16, 0, 0);
}

// ---------------- fp32 -> bf16 cast (vectorized x4) ----------------
__global__ __launch_bounds__(256)
void cast_f2b(const float* __restrict__ in, unsigned short* __restrict__ out, int n4)
{
    const int i = blockIdx.x * 256 + threadIdx.x;
    if (i < n4) {
        const float4 v = *reinterpret_cast<const float4*>(in + (size_t)i * 4);
        ushort4v o = {f2bf(v.x), f2bf(v.y), f2bf(v.z), f2bf(v.w)};
        *reinterpret_cast<ushort4v*>(out + (size_t)i * 4) = o;
    }
}

// ---------------- conv2 weight reorder: wr[o][j*I+c] = w[o][c][j], fp32->bf16 ----------------
__global__ __launch_bounds__(256)
void w3reorder(const float* __restrict__ w, unsigned short* __restrict__ wr, int O, int I)
{
    const int idx = blockIdx.x * 256 + threadIdx.x;
    if (idx < O * I * 3) {
        const int o = idx / (I * 3), rem = idx % (I * 3);
        const int j = rem / I, c = rem % I;
        wr[idx] = f2bf(w[(size_t)o * I * 3 + c * 3 + j]);
    }
}

// ---------------- zero the 2 pad rows per batch of the conv2 input buffers ----------------
__global__ __launch_bounds__(256)
void zero_pad(unsigned short* __restrict__ pq, unsigned short* __restrict__ pk)
{
    const int t = blockIdx.x * 256 + threadIdx.x;
    if (t < 2 * 2 * LATENT) {
        const int b = t / (2 * LATENT), r = (t % (2 * LATENT)) / LATENT, c = t % LATENT;
        pq[((size_t)b * SP + r) * LATENT + c] = 0;
    }
    if (t < 2 * 2 * KVD) {
        const int b = t / (2 * KVD), r = (t % (2 * KVD)) / KVD, c = t % KVD;
        pk[((size_t)b * SP + r) * KVD + c] = 0;
    }
}

// ---------------- merge split-K partials: out = p0 + p1 (+ bias) ----------------
__global__ __launch_bounds__(256)
void add2(const float* __restrict__ p0, const float* __restrict__ p1,
          const float* __restrict__ bias, float* __restrict__ out, int n4, int ncols)
{
    const int i = blockIdx.x * 256 + threadIdx.x;
    if (i < n4) {
        const float4 a = *reinterpret_cast<const float4*>(p0 + (size_t)i * 4);
        const float4 b = *reinterpret_cast<const float4*>(p1 + (size_t)i * 4);
        float4 o = make_float4(a.x + b.x, a.y + b.y, a.z + b.z, a.w + b.w);
        if (bias != nullptr) {
            const int col = (i * 4) % ncols;
            o.x += bias[col]; o.y += bias[col + 1]; o.z += bias[col + 2]; o.w += bias[col + 3];
        }
        *reinterpret_cast<float4*>(out + (size_t)i * 4) = o;
    }
}

// ---------------- RoPE cos/sin table ----------------
__global__ __launch_bounds__(256)
void rope_tab(float2* __restrict__ tab)
{
    const int idx = blockIdx.x * 256 + threadIdx.x;   // SEQ*32
    const int s = idx >> 5, i = idx & 31;
    const float inv = powf(10000.f, -(float)(2 * i) * (1.f / HD));
    const float ang = (float)s * inv;
    tab[idx] = make_float2(cosf(ang), sinf(ang));
}

// ---------------- 256x256 deep-pipelined bf16 GEMM (counted vmcnt, 3-buffer LDS) ----------------
// C[M][N] = A[M][K] @ W[N][K]^T, fp32 out, no bias. 8 waves (2M x 4N), BK=32.
// 3 LDS buffers rotate: compute buf[kt%3] while kt+1 lands and kt+2 is issued.
// Top-of-tile wait is vmcnt(4) (kt+1 stays in flight) -- never a full drain.
// Race-freedom: stage(kt+2) writes buf[(kt+2)%3]; its last readers were K-tile
// kt-1, whose reads completed before iteration kt-1's trailing barrier.
// T2 swizzle: 16B-slot ^= (row>>1)&3, applied to BOTH the global source (staging)
// and the ds_read address (rule #21); involution -> reads land 2 lanes/bank (free).
__global__ __launch_bounds__(512)
void gemm256(const unsigned short* __restrict__ A, const unsigned short* __restrict__ W,
             float* __restrict__ C, int M, int N, int K, int klen, size_t pstride)
{
    __shared__ unsigned short SA[3][256 * 32];
    __shared__ unsigned short SBm[3][256 * 32];
    const int gx = gridDim.x;
    const int nwg = gx * gridDim.y;
    const int lin = blockIdx.y * gx + blockIdx.x;
    const int swz = (lin & 7) * (nwg >> 3) + (lin >> 3);
    const int n0 = (swz % gx) * 256, m0 = (swz / gx) * 256;
    const int koff = blockIdx.z * klen;
    C += (size_t)blockIdx.z * pstride;
    const int tid = threadIdx.x;
    const int wid = tid >> 6, lane = tid & 63;
    const int lg = lane >> 4, lr = lane & 15;
    const int wm = wid >> 2, wn = wid & 3;
    const int NT = klen / 32;

    f32x4 acc[8][4];
    #pragma unroll
    for (int i = 0; i < 8; i++)
        #pragma unroll
        for (int j = 0; j < 4; j++) acc[i][j] = (f32x4){0.f, 0.f, 0.f, 0.f};

    // staging: 1024 16B-chunks per matrix per K-tile; thread tid handles chunks {tid, tid+512}.
    // chunk c: row=c>>2, slot=c&3; source col-chunk = slot ^ ((row>>1)&3) (inverse swizzle).
    auto stage1 = [&](int buf, int kt, int i) {
        const int c = i * 512 + tid;
        const int row = c >> 2, slot = c & 3;
        const int scol = (slot ^ ((row >> 1) & 3)) << 3;   // bf16 elems
        gload_lds16(A + (size_t)(m0 + row) * K + koff + kt * 32 + scol, &SA[buf][c * 8]);
        gload_lds16(W + (size_t)(n0 + row) * K + koff + kt * 32 + scol, &SBm[buf][c * 8]);
    };

    stage1(0, 0, 0); stage1(0, 0, 1);
    stage1(1, 1, 0); stage1(1, 1, 1);

    for (int kt = 0; kt < NT; ++kt) {
        const int cur = kt % 3;
        const int nb = (kt + 2) % 3;
        const bool pre = (kt + 2) < NT;
        if (kt + 1 < NT) asm volatile("s_waitcnt vmcnt(4)" ::: "memory");
        else             asm volatile("s_waitcnt vmcnt(0)" ::: "memory");
        __builtin_amdgcn_sched_barrier(0);
        __builtin_amdgcn_s_barrier();
        asm volatile("" ::: "memory");

        short8v bfr[4];
        #pragma unroll
        for (int ni = 0; ni < 4; ni++) {
            const int br = wn * 64 + ni * 16 + lr;
            bfr[ni] = *reinterpret_cast<const short8v*>(&SBm[cur][br * 32 + ((lg ^ ((br >> 1) & 3)) << 3)]);
        }
        #pragma unroll
        for (int q = 0; q < 4; q++) {
            if (q == 0 && pre) stage1(nb, kt + 2, 0);
            if (q == 2 && pre) stage1(nb, kt + 2, 1);
            const int ar0 = wm * 128 + (2 * q) * 16 + lr;
            const int ar1 = ar0 + 16;
            const short8v a0 = *reinterpret_cast<const short8v*>(&SA[cur][ar0 * 32 + ((lg ^ ((ar0 >> 1) & 3)) << 3)]);
            const short8v a1 = *reinterpret_cast<const short8v*>(&SA[cur][ar1 * 32 + ((lg ^ ((ar1 >> 1) & 3)) << 3)]);
            __builtin_amdgcn_s_setprio(1);
            #pragma unroll
            for (int ni = 0; ni < 4; ni++) {
                acc[2 * q][ni]     = __builtin_amdgcn_mfma_f32_16x16x32_bf16(a0, bfr[ni], acc[2 * q][ni], 0, 0, 0);
                acc[2 * q + 1][ni] = __builtin_amdgcn_mfma_f32_16x16x32_bf16(a1, bfr[ni], acc[2 * q + 1][ni], 0, 0, 0);
            }
            __builtin_amdgcn_s_setprio(0);
        }
        asm volatile("" ::: "memory");
        __builtin_amdgcn_s_barrier();
    }

    #pragma unroll
    for (int ni = 0; ni < 4; ni++) {
        const int col = n0 + wn * 64 + ni * 16 + lr;
        #pragma unroll
        for (int mi = 0; mi < 8; mi++)
            #pragma unroll
            for (int r = 0; r < 4; r++)
                C[(size_t)(m0 + wm * 128 + mi * 16 + lg * 4 + r) * N + col] = acc[mi][ni][r];
    }
}

// ---------------- bf16 MFMA GEMM: 128x128 tile, 2-phase (kept for conv2) ----------------
template<int CONV>
__global__ __launch_bounds__(256)
void gemm_bf16(const unsigned short* __restrict__ A, const unsigned short* __restrict__ W,
               const float* __restrict__ bias, float* __restrict__ C,
               int M, int N, int K, int Cch, int klen, size_t pstride)
{
    __shared__ unsigned short Abuf[2][128 * 32];
    __shared__ unsigned short Bbuf[2][128 * 32];
    const int gx = gridDim.x;
    const int nwg = gx * gridDim.y;
    const int lin = blockIdx.y * gx + blockIdx.x;
    const int swz = (lin & 7) * (nwg >> 3) + (lin >> 3);
    const int n0 = (swz % gx) * 128, m0 = (swz / gx) * 128;
    const int koff = blockIdx.z * klen;
    C += (size_t)blockIdx.z * pstride;
    const int tid = threadIdx.x;
    const int wave = tid >> 6, lane = tid & 63;
    const int lg = lane >> 4, lr = lane & 15;
    const int wm = (wave & 1) * 64, wn = (wave >> 1) * 64;
    const int sr = wave * 32 + (lane >> 2);
    const int sc = (lane & 3) * 8;
    const int bb = m0 / SEQ, s0 = m0 % SEQ;

    const int NT = klen / 32;
    f32x4 acc[4][4];
    #pragma unroll
    for (int i = 0; i < 4; i++)
        #pragma unroll
        for (int j = 0; j < 4; j++) acc[i][j] = (f32x4){0.f, 0.f, 0.f, 0.f};

    auto stage = [&](int buf, int kt) {
        const int k0 = koff + kt * 32;
        const unsigned short* ga0;
        if (!CONV) {
            ga0 = A + (size_t)(m0 + sr) * K + k0 + sc;
        } else {
            const int j = k0 / Cch, c0 = k0 - j * Cch;
            ga0 = A + (size_t)(bb * SP + s0 + j + sr) * Cch + c0 + sc;
        }
        const unsigned short* gb0 = W + (size_t)(n0 + sr) * K + k0 + sc;
        const size_t astep = (size_t)16 * (CONV ? Cch : K);
        #pragma unroll
        for (int i = 0; i < 2; i++) {
            gload_lds16(ga0 + i * astep, &Abuf[buf][(wave * 2 + i) * 512]);
            gload_lds16(gb0 + (size_t)i * 16 * K, &Bbuf[buf][(wave * 2 + i) * 512]);
        }
    };

    stage(0, 0);
    __syncthreads();
    int cur = 0;
    for (int kt = 0; kt < NT; ++kt) {
        if (kt + 1 < NT) stage(cur ^ 1, kt + 1);
        short8v af[4], bf[4];
        #pragma unroll
        for (int mi = 0; mi < 4; mi++)
            af[mi] = *reinterpret_cast<const short8v*>(&Abuf[cur][(wm + mi * 16 + lr) * 32 + lg * 8]);
        #pragma unroll
        for (int ni = 0; ni < 4; ni++)
            bf[ni] = *reinterpret_cast<const short8v*>(&Bbuf[cur][(wn + ni * 16 + lr) * 32 + lg * 8]);
        #pragma unroll
        for (int mi = 0; mi < 4; mi++)
            #pragma unroll
            for (int ni = 0; ni < 4; ni++)
                acc[mi][ni] = __builtin_amdgcn_mfma_f32_16x16x32_bf16(af[mi], bf[ni], acc[mi][ni], 0, 0, 0);
        __syncthreads();
        cur ^= 1;
    }

    #pragma unroll
    for (int ni = 0; ni < 4; ni++) {
        const int col = n0 + wn + ni * 16 + lr;
        const float bv = bias ? bias[col] : 0.f;
        #pragma unroll
        for (int mi = 0; mi < 4; mi++)
            #pragma unroll
            for (int r = 0; r < 4; r++)
                C[(size_t)(m0 + wm + mi * 16 + lg * 4 + r) * N + col] = acc[mi][ni][r] + bv;
    }
}

// ---------------- grouped causal conv1 -> bf16 padded [b][SP][CH] (rows 0,1 zero) ----------------
__global__ __launch_bounds__(256)
void conv1_grouped(const float* __restrict__ qkv, int coloff,
                   const float* __restrict__ w, const float* __restrict__ bias,
                   unsigned short* __restrict__ out, int CH)
{
    const int t0 = blockIdx.x * 64;
    const int b  = blockIdx.y;
    const int g  = blockIdx.z;
    __shared__ float xs[66][64];
    for (int idx = threadIdx.x; idx < 66 * 64; idx += 256) {
        const int i = idx >> 6, ic = idx & 63;
        const int tt = t0 + i - 2;
        xs[i][ic] = (tt >= 0) ? qkv[(size_t)(b * SEQ + tt) * QKVN + coloff + g * 64 + ic] : 0.f;
    }
    __syncthreads();
    const int oc = threadIdx.x & 63;
    const int ibase = (threadIdx.x >> 6) * 16;
    float acc[16];
    const float bv = bias[g * 64 + oc];
    #pragma unroll
    for (int i = 0; i < 16; i++) acc[i] = bv;
    const float* wp = w + (size_t)(g * 64 + oc) * 192;
    for (int ic = 0; ic < 64; ic++) {
        const float w0 = wp[ic * 3 + 0], w1 = wp[ic * 3 + 1], w2 = wp[ic * 3 + 2];
        float xv[18];
        #pragma unroll
        for (int r = 0; r < 18; r++) xv[r] = xs[ibase + r][ic];
        #pragma unroll
        for (int i = 0; i < 16; i++) acc[i] += w0 * xv[i] + w1 * xv[i + 1] + w2 * xv[i + 2];
    }
    #pragma unroll
    for (int i = 0; i < 16; i++)
        out[((size_t)b * SP + 2 + t0 + ibase + i) * CH + g * 64 + oc] = f2bf(acc[i]);
}

// ---------------- head means + shifted-v build (row-major bf16) ----------------
__global__ __launch_bounds__(64)
void meanv_kernel(const float* __restrict__ qkv, float* __restrict__ qmean,
                  float* __restrict__ kmean, unsigned short* __restrict__ vRow)
{
    const int t = blockIdx.x, d = threadIdx.x;
    const int b = t >> 11, s = t & (SEQ - 1);
    const float* row = qkv + (size_t)t * QKVN;
    float qs = 0.f;
    #pragma unroll
    for (int h = 0; h < NH; h++) qs += row[h * 64 + d];
    qmean[t * 64 + d] = qs * (1.f / NH);
    float ks = 0.f;
    #pragma unroll
    for (int h = 0; h < NKV; h++) ks += row[LATENT + h * 64 + d];
    kmean[t * 64 + d] = ks * (1.f / NKV);
    #pragma unroll
    for (int g = 0; g < NKV; g++) {
        const int c = g * 64 + d;
        float v;
        if (c < 128) v = row[LATENT + KVD + c];
        else         v = (s > 0) ? qkv[(size_t)(t - 1) * QKVN + LATENT + KVD + 128 + (c - 128)] : 0.f;
        vRow[((size_t)(b * NKV + g) * SEQ + s) * 64 + d] = f2bf(v);
    }
}

// ---------------- V transpose to d-major: vTb[bg][d][S] ----------------
__global__ __launch_bounds__(256)
void vtrans(const unsigned short* __restrict__ vRow, unsigned short* __restrict__ vTb)
{
    const int s0 = blockIdx.x * 64;
    const int bg = blockIdx.y;
    __shared__ unsigned short t[64][72];
    const int tid = threadIdx.x;
    {
        const int r = tid >> 2, c0 = (tid & 3) * 16;
        const unsigned short* p = vRow + ((size_t)bg * SEQ + s0 + r) * 64 + c0;
        const short8v a = *reinterpret_cast<const short8v*>(p);
        const short8v bv = *reinterpret_cast<const short8v*>(p + 8);
        #pragma unroll
        for (int j = 0; j < 8; j++) { t[r][c0 + j] = (unsigned short)a[j]; t[r][c0 + 8 + j] = (unsigned short)bv[j]; }
    }
    __syncthreads();
    {
        const int d = tid >> 2, ss = (tid & 3) * 16;
        short8v o0, o1;
        #pragma unroll
        for (int j = 0; j < 8; j++) { o0[j] = (short)t[ss + j][d]; o1[j] = (short)t[ss + 8 + j][d]; }
        unsigned short* op = vTb + ((size_t)bg * 64 + d) * SEQ + s0 + ss;
        *reinterpret_cast<short8v*>(op) = o0;
        *reinterpret_cast<short8v*>(op + 8) = o1;
    }
}

// ---------------- fused conv2-partial merge + bias, +0.5*mean, l2norm, rope(table) -> bf16 ----------------
__global__ __launch_bounds__(64)
void qk_final(const float* __restrict__ qc2a, const float* __restrict__ qc2b,
              const float* __restrict__ kc2a, const float* __restrict__ kc2b,
              const float* __restrict__ qbias, const float* __restrict__ kbias,
              const float* __restrict__ qmean, const float* __restrict__ kmean,
              const float* __restrict__ key_temp, const float2* __restrict__ rtab,
              unsigned short* __restrict__ qTb, unsigned short* __restrict__ kTb)
{
    const int t = blockIdx.x, hh = blockIdx.y, d = threadIdx.x;
    const int b = t >> 11, s = t & (SEQ - 1);
    float val;
    if (hh < NH) {
        const size_t off = (size_t)t * LATENT + hh * 64 + d;
        val = qc2a[off] + qc2b[off] + qbias[hh * 64 + d] + 0.5f * kmean[t * 64 + d];
    } else {
        const size_t off = (size_t)t * KVD + (hh - NH) * 64 + d;
        val = kc2a[off] + kc2b[off] + kbias[(hh - NH) * 64 + d] + 0.5f * qmean[t * 64 + d];
    }
    float ss = val * val;
    #pragma unroll
    for (int off = 32; off >= 1; off >>= 1) ss += __shfl_xor(ss, off);
    const float n = sqrtf(ss);
    val = val / fmaxf(n, 1e-12f);
    if (hh >= NH) val *= key_temp[0];
    const float2 cs = rtab[s * 32 + (d >> 1)];
    const float cv = cs.x, sv = cs.y;
    const float partner = __shfl_xor(val, 1);
    const float x1 = (d & 1) ? partner : val;
    const float x2 = (d & 1) ? val : partner;
    const float o = (d & 1) ? (x1 * sv + x2 * cv) : (x1 * cv - x2 * sv);
    if (hh < NH) qTb[((size_t)(b * NH + hh) * SEQ + s) * 64 + d] = f2bf(o);
    else         kTb[((size_t)(b * NKV + (hh - NH)) * SEQ + s) * 64 + d] = f2bf(o);
}

// ---------------- MFMA causal GQA attention: 4-wave block shares K/V via LDS, BK=64 ----------------
__global__ __launch_bounds__(256)
void attn_mfma(const unsigned short* __restrict__ qTb, const unsigned short* __restrict__ kTb,
               const unsigned short* __restrict__ vTb, unsigned short* __restrict__ attn_out)
{
    const int wg = blockIdx.x;
    int bh, blk;
    if (wg < 256) {
        const int xcd = wg & 7, i = wg >> 3;
        bh = (xcd << 2) | (i >> 3);
        blk = 15 - (i & 7);          // 8..15
    } else {
        const int u = wg - 256;
        const int xcd = u & 7, i = u >> 3;
        bh = (xcd << 2) | (i >> 3);
        blk = i & 7;                 // 0..7
    }
    const int b = bh >> 4, h = bh & 15, g = h >> 2;
    const int tid = threadIdx.x;
    const int wave = tid >> 6, lane = tid & 63;
    const int lg = lane >> 4, lr = lane & 15;
    const int qt = blk * 4 + wave;
    const int q0 = qt * 32;
    const int ctot2 = (blk + 1) * 2;     // 64-key phases

    __shared__ __align__(16) unsigned short SB[2][16][512];

    short8v qf[2][2];
    const unsigned short* qbase = qTb + ((size_t)(b * NH + h) * SEQ + q0) * 64;
    #pragma unroll
    for (int mf = 0; mf < 2; mf++)
        #pragma unroll
        for (int dc = 0; dc < 2; dc++)
            qf[mf][dc] = *reinterpret_cast<const short8v*>(qbase + (size_t)(mf * 16 + lr) * 64 + dc * 32 + lg * 8);

    f32x4 acc[2][4];
    float lsum[2] = {0.f, 0.f};
    #pragma unroll
    for (int mf = 0; mf < 2; mf++)
        #pragma unroll
        for (int dt = 0; dt < 4; dt++) acc[mf][dt] = (f32x4){0.f, 0.f, 0.f, 0.f};

    const unsigned short* kbase = kTb + (size_t)(b * NKV + g) * SEQ * 64;
    const unsigned short* vbase = vTb + (size_t)(b * NKV + g) * 64 * SEQ;
    const float EC = 0.125f * 1.44269504f;
    const int src01 = ((lg & 1) << 5) + lr;
    const int src23 = src01 + 16;
    const bool hi = (lg >= 2);

    auto stage64 = [&](int buf, int cc) {
        const int kb = cc * 64;
        #pragma unroll
        for (int i = 0; i < 4; i++) {
            const int ch = wave * 4 + i;
            const int st = ch >> 3, chl = ch & 7;
            const int k0 = kb + st * 32;
            const unsigned short* src;
            if (chl < 4) src = kbase + (size_t)(k0 + (chl >> 1) * 16 + lr) * 64 + (chl & 1) * 32 + lg * 8;
            else         src = vbase + (size_t)((chl - 4) * 16 + lr) * SEQ + k0 + lg * 8;
            gload_lds16(src, &SB[buf][ch][lane * 8]);
        }
    };

    stage64(0, 0);
    __syncthreads();
    int cur = 0;
    for (int cc = 0; cc < ctot2; ++cc) {
        if (cc + 1 < ctot2) stage64(cur ^ 1, cc + 1);
        #pragma unroll
        for (int st = 0; st < 2; ++st) {
            const int c = cc * 2 + st;
            if (c > qt) continue;
            const int k0 = c * 32;
            short8v kf[2][2], vf[4];
            #pragma unroll
            for (int kt = 0; kt < 2; kt++)
                #pragma unroll
                for (int dc = 0; dc < 2; dc++)
                    kf[kt][dc] = *reinterpret_cast<const short8v*>(&SB[cur][st * 8 + kt * 2 + dc][lane * 8]);
            #pragma unroll
            for (int dt = 0; dt < 4; dt++)
                vf[dt] = *reinterpret_cast<const short8v*>(&SB[cur][st * 8 + 4 + dt][lane * 8]);

            const bool diag = (c == qt);
            #pragma unroll
            for (int mf = 0; mf < 2; mf++) {
                f32x4 z0 = (f32x4){0.f, 0.f, 0.f, 0.f}, z1 = (f32x4){0.f, 0.f, 0.f, 0.f};
                __builtin_amdgcn_s_setprio(1);
                z0 = __builtin_amdgcn_mfma_f32_16x16x32_bf16(kf[0][0], qf[mf][0], z0, 0, 0, 0);
                z0 = __builtin_amdgcn_mfma_f32_16x16x32_bf16(kf[0][1], qf[mf][1], z0, 0, 0, 0);
                z1 = __builtin_amdgcn_mfma_f32_16x16x32_bf16(kf[1][0], qf[mf][0], z1, 0, 0, 0);
                z1 = __builtin_amdgcn_mfma_f32_16x16x32_bf16(kf[1][1], qf[mf][1], z1, 0, 0, 0);
                __builtin_amdgcn_s_setprio(0);
                float p0[4], p1[4];
                #pragma unroll
                for (int r = 0; r < 4; r++) {
                    p0[r] = exp2f(z0[r] * EC);
                    p1[r] = exp2f(z1[r] * EC);
                }
                if (diag) {
                    const int q = q0 + mf * 16 + lr;
                    #pragma unroll
                    for (int r = 0; r < 4; r++) {
                        if (k0 + 4 * lg + r > q)      p0[r] = 0.f;
                        if (k0 + 16 + 4 * lg + r > q) p1[r] = 0.f;
                    }
                }
                lsum[mf] += (p0[0] + p0[1]) + (p0[2] + p0[3]) + (p1[0] + p1[1]) + (p1[2] + p1[3]);
                const unsigned W00 = cvt_pk_bf16(p0[0], p0[1]);
                const unsigned W01 = cvt_pk_bf16(p0[2], p0[3]);
                const unsigned W10 = cvt_pk_bf16(p1[0], p1[1]);
                const unsigned W11 = cvt_pk_bf16(p1[2], p1[3]);
                const unsigned a0 = __shfl(W00, src01), b0 = __shfl(W10, src01);
                const unsigned a1 = __shfl(W01, src01), b1 = __shfl(W11, src01);
                const unsigned a2 = __shfl(W00, src23), b2 = __shfl(W10, src23);
                const unsigned a3 = __shfl(W01, src23), b3 = __shfl(W11, src23);
                uint4v pw;
                pw.x = hi ? b0 : a0;
                pw.y = hi ? b1 : a1;
                pw.z = hi ? b2 : a2;
                pw.w = hi ? b3 : a3;
                const short8v pa = __builtin_bit_cast(short8v, pw);
                __builtin_amdgcn_s_setprio(1);
                #pragma unroll
                for (int dt = 0; dt < 4; dt++)
                    acc[mf][dt] = __builtin_amdgcn_mfma_f32_16x16x32_bf16(pa, vf[dt], acc[mf][dt], 0, 0, 0);
                __builtin_amdgcn_s_setprio(0);
            }
        }
        __syncthreads();
        cur ^= 1;
    }

    float den[2];
    #pragma unroll
    for (int mf = 0; mf < 2; mf++) {
        float s = lsum[mf];
        s += __shfl_xor(s, 16); s += __shfl_xor(s, 32);
        den[mf] = s;
    }

    #pragma unroll
    for (int mf = 0; mf < 2; mf++) {
        float dinv[4];
        #pragma unroll
        for (int r = 0; r < 4; r++) dinv[r] = 1.f / __shfl(den[mf], 4 * lg + r);
        #pragma unroll
        for (int dt = 0; dt < 4; dt++)
            #pragma unroll
            for (int r = 0; r < 4; r++) {
                const int q = q0 + mf * 16 + 4 * lg + r;
                attn_out[(size_t)(b * SEQ + q) * LATENT + h * 64 + dt * 16 + lr] = f2bf(acc[mf][dt][r] * dinv[r]);
            }
    }
}

extern "C" void kernel_launch(void* const* d_in, const int* in_sizes, int n_in,
                              void* d_out, int out_size, void* d_ws, size_t ws_size,
                              hipStream_t stream)
{
    const float* x       = (const float*)d_in[0];
    const float* w_qkv   = (const float*)d_in[1];
    const float* w_o     = (const float*)d_in[2];
    const float* qc1_w   = (const float*)d_in[3];
    const float* qc1_b   = (const float*)d_in[4];
    const float* qc2_w   = (const float*)d_in[5];
    const float* qc2_b   = (const float*)d_in[6];
    const float* kc1_w   = (const float*)d_in[7];
    const float* kc1_b   = (const float*)d_in[8];
    const float* kc2_w   = (const float*)d_in[9];
    const float* kc2_b   = (const float*)d_in[10];
    const float* key_temp = (const float*)d_in[11];

    // --- workspace layout (aliased by lifetime; byte offsets noted) ---
    char* wsb = (char*)d_ws;
    float* qkv = (float*)wsb;                 wsb += (size_t)BS * QKVN * 4;     // [0, 25165824)
    float* qc2 = qkv;                                                            // alias (qkv dead after conv1)
    float* kc2 = (float*)((char*)qkv + (size_t)BS * LATENT * 4);                 // [16777216, 20971520)
    unsigned short* pq  = (unsigned short*)wsb;  wsb += (size_t)NB * SP * LATENT * 2;  // [25165824, 33562624)
    unsigned short* pk  = (unsigned short*)wsb;  wsb += (size_t)NB * SP * KVD * 2;     // [33562624, 35661824)
    float* qmean = (float*)wsb;  wsb += (size_t)BS * HD * 4;
    float* kmean = (float*)wsb;  wsb += (size_t)BS * HD * 4;
    unsigned short* qTb  = (unsigned short*)wsb;  wsb += (size_t)BS * LATENT * 2;
    unsigned short* kTb  = (unsigned short*)wsb;  wsb += (size_t)BS * KVD * 2;
    unsigned short* vRow = (unsigned short*)wsb;  wsb += (size_t)BS * KVD * 2;
    unsigned short* vTb  = (unsigned short*)wsb;  wsb += (size_t)BS * KVD * 2;   // ends 52439040
    unsigned short* xb   = (unsigned short*)wsb;  wsb += (size_t)BS * DIMX * 2;  // [52439040, 85993472)
    unsigned short* attnb  = xb;
    unsigned short* qc2wr  = (unsigned short*)((char*)xb + (size_t)BS * LATENT * 2);
    unsigned short* kc2wr  = (unsigned short*)((char*)qc2wr + (size_t)LATENT * LATENT * 3 * 2);
    unsigned short* wqkvb = (unsigned short*)wsb;  wsb += (size_t)QKVN * DIMX * 2;  // [85993472, 98576384)
    unsigned short* wob   = wqkvb;

    const size_t QKV_PS = (size_t)BS * QKVN;                      // qkv p1 at qkv+M*N (pre-meanv region)
    float* qc2p1 = (float*)((char*)d_ws + 67512320);              // xb tail (dead), 16.7MB
    float* kc2p1 = (float*)((char*)d_ws + (size_t)BS * QKVN * 4); // pq region (dead after conv2-q GEMM)
    const size_t QC2_PS = (size_t)(qc2p1 - qc2);
    const size_t KC2_PS = (size_t)(kc2p1 - kc2);
    float2* rtab = (float2*)vRow;   // rope table in dead vRow region

    float* outp = (float*)d_out;

    // 1. casts for qkv GEMM
    cast_f2b<<<dim3(BS * DIMX / 4 / 256), 256, 0, stream>>>(x, xb, BS * DIMX / 4);
    cast_f2b<<<dim3(QKVN * DIMX / 4 / 256), 256, 0, stream>>>(w_qkv, wqkvb, QKVN * DIMX / 4);
    // 2. qkv projection: deep-pipelined 256^2 GEMM, split-K=2 (192 blocks) + merge
    gemm256<<<dim3(QKVN / 256, BS / 256, 2), 512, 0, stream>>>(xb, wqkvb, qkv, BS, QKVN, DIMX, DIMX / 2, QKV_PS);
    add2<<<dim3(BS * QKVN / 4 / 256), 256, 0, stream>>>(qkv, qkv + QKV_PS, nullptr, qkv, BS * QKVN / 4, 4);
    // 3. prep for later GEMMs (xb/wqkvb dead)
    cast_f2b<<<dim3(DIMX * LATENT / 4 / 256), 256, 0, stream>>>(w_o, wob, DIMX * LATENT / 4);
    w3reorder<<<dim3((LATENT * LATENT * 3 + 255) / 256), 256, 0, stream>>>(qc2_w, qc2wr, LATENT, LATENT);
    w3reorder<<<dim3((KVD * KVD * 3 + 255) / 256), 256, 0, stream>>>(kc2_w, kc2wr, KVD, KVD);
    // 4. means + shifted v, V transpose, rope table, pads
    meanv_kernel<<<dim3(BS), 64, 0, stream>>>(qkv, qmean, kmean, vRow);
    vtrans<<<dim3(SEQ / 64, NB * NKV), 256, 0, stream>>>(vRow, vTb);
    rope_tab<<<dim3(SEQ * 32 / 256), 256, 0, stream>>>(rtab);
    zero_pad<<<dim3(16), 256, 0, stream>>>(pq, pk);
    // 5. grouped conv1 -> padded bf16
    conv1_grouped<<<dim3(SEQ / 64, NB, NH),  256, 0, stream>>>(qkv, 0,      qc1_w, qc1_b, pq, LATENT);
    conv1_grouped<<<dim3(SEQ / 64, NB, NKV), 256, 0, stream>>>(qkv, LATENT, kc1_w, kc1_b, pk, KVD);
    // 6. conv2 as split-K bf16 GEMMs; partials merged inside qk_final
    gemm_bf16<1><<<dim3(LATENT / 128, BS / 128, 2), 256, 0, stream>>>(pq, qc2wr, nullptr, qc2, BS, LATENT, LATENT * 3, LATENT, LATENT * 3 / 2, QC2_PS);
    gemm_bf16<1><<<dim3(KVD / 128, BS / 128, 2), 256, 0, stream>>>(pk, kc2wr, nullptr, kc2, BS, KVD, KVD * 3, KVD, KVD * 3 / 2, KC2_PS);
    // 7. fused merge+bias, +0.5*mean, l2norm, rope
    qk_final<<<dim3(BS, NH + NKV), 64, 0, stream>>>(qc2, qc2p1, kc2, kc2p1, qc2_b, kc2_b,
                                                    qmean, kmean, key_temp, rtab, qTb, kTb);
    // 8. attention (work-balanced pairing, BK=64)
    attn_mfma<<<dim3(512), 256, 0, stream>>>(qTb, kTb, vTb, attnb);
    // 9. output projection: deep-pipelined 256^2 GEMM (256 blocks, 1/CU)
    gemm256<<<dim3(DIMX / 256, BS / 256, 1), 512, 0, stream>>>(attnb, wob, outp, BS, DIMX, LATENT, LATENT, 0);
}

// Round 13
// 377.691 us; speedup vs baseline: 1.0508x; 1.0508x over previous
//
#include <hip/hip_runtime.h>
#include <hip/hip_bf16.h>
#include <cstddef>

#define NB 2
#define SEQ 2048
#define DIMX 4096
#define NH 16
#define NKV 4
#define HD 64
#define LATENT 1024
#define KVD 256
#define QKVN 1536
#define BS (NB*SEQ)
#define SP (SEQ+2)   // padded token rows per batch for conv2 input

typedef __attribute__((ext_vector_type(8))) short short8v;   // 8 bf16 = 4 VGPR
typedef __attribute__((ext_vector_type(4))) float f32x4;
typedef __attribute__((ext_vector_type(4))) unsigned short ushort4v;
typedef __attribute__((ext_vector_type(4))) unsigned int uint4v;

static __device__ __forceinline__ unsigned short f2bf(float f) {
    union { float f; unsigned u; } v; v.f = f;
    unsigned r = v.u + 0x7fffu + ((v.u >> 16) & 1u);
    return (unsigned short)(r >> 16);
}

static __device__ __forceinline__ unsigned cvt_pk_bf16(float lo, float hi) {
    unsigned r;
    asm("v_cvt_pk_bf16_f32 %0, %1, %2" : "=v"(r) : "v"(lo), "v"(hi));
    return r;
}

static __device__ __forceinline__ void gload_lds16(const unsigned short* g, unsigned short* l) {
    __builtin_amdgcn_global_load_lds((const __attribute__((address_space(1))) void*)g,
                                     (__attribute__((address_space(3))) void*)l, 16, 0, 0);
}

// ---------------- fp32 -> bf16 cast (vectorized x4) ----------------
__global__ __launch_bounds__(256)
void cast_f2b(const float* __restrict__ in, unsigned short* __restrict__ out, int n4)
{
    const int i = blockIdx.x * 256 + threadIdx.x;
    if (i < n4) {
        const float4 v = *reinterpret_cast<const float4*>(in + (size_t)i * 4);
        ushort4v o = {f2bf(v.x), f2bf(v.y), f2bf(v.z), f2bf(v.w)};
        *reinterpret_cast<ushort4v*>(out + (size_t)i * 4) = o;
    }
}

// ---------------- conv2 weight reorder: wr[o][j*I+c] = w[o][c][j], fp32->bf16 ----------------
__global__ __launch_bounds__(256)
void w3reorder(const float* __restrict__ w, unsigned short* __restrict__ wr, int O, int I)
{
    const int idx = blockIdx.x * 256 + threadIdx.x;
    if (idx < O * I * 3) {
        const int o = idx / (I * 3), rem = idx % (I * 3);
        const int j = rem / I, c = rem % I;
        wr[idx] = f2bf(w[(size_t)o * I * 3 + c * 3 + j]);
    }
}

// ---------------- zero the 2 pad rows per batch of the conv2 input buffers ----------------
__global__ __launch_bounds__(256)
void zero_pad(unsigned short* __restrict__ pq, unsigned short* __restrict__ pk)
{
    const int t = blockIdx.x * 256 + threadIdx.x;
    if (t < 2 * 2 * LATENT) {
        const int b = t / (2 * LATENT), r = (t % (2 * LATENT)) / LATENT, c = t % LATENT;
        pq[((size_t)b * SP + r) * LATENT + c] = 0;
    }
    if (t < 2 * 2 * KVD) {
        const int b = t / (2 * KVD), r = (t % (2 * KVD)) / KVD, c = t % KVD;
        pk[((size_t)b * SP + r) * KVD + c] = 0;
    }
}

// ---------------- RoPE cos/sin table ----------------
__global__ __launch_bounds__(256)
void rope_tab(float2* __restrict__ tab)
{
    const int idx = blockIdx.x * 256 + threadIdx.x;   // SEQ*32
    const int s = idx >> 5, i = idx & 31;
    const float inv = powf(10000.f, -(float)(2 * i) * (1.f / HD));
    const float ang = (float)s * inv;
    tab[idx] = make_float2(cosf(ang), sinf(ang));
}

// ---------------- bf16 MFMA GEMM: C[M][N] = A[M][K] @ W[N][K]^T, fp32 out ----------------
// 128x128 tile, BK=32, 2-phase double-buffered global_load_lds staging, split-K via grid.z.
template<int CONV>
__global__ __launch_bounds__(256)
void gemm_bf16(const unsigned short* __restrict__ A, const unsigned short* __restrict__ W,
               const float* __restrict__ bias, float* __restrict__ C,
               int M, int N, int K, int Cch, int klen, size_t pstride)
{
    __shared__ unsigned short Abuf[2][128 * 32];
    __shared__ unsigned short Bbuf[2][128 * 32];
    const int gx = gridDim.x;
    const int nwg = gx * gridDim.y;
    const int lin = blockIdx.y * gx + blockIdx.x;
    const int swz = (lin & 7) * (nwg >> 3) + (lin >> 3);
    const int n0 = (swz % gx) * 128, m0 = (swz / gx) * 128;
    const int koff = blockIdx.z * klen;
    C += (size_t)blockIdx.z * pstride;
    const int tid = threadIdx.x;
    const int wave = tid >> 6, lane = tid & 63;
    const int lg = lane >> 4, lr = lane & 15;
    const int wm = (wave & 1) * 64, wn = (wave >> 1) * 64;
    const int sr = wave * 32 + (lane >> 2);
    const int sc = (lane & 3) * 8;
    const int bb = m0 / SEQ, s0 = m0 % SEQ;

    const int NT = klen / 32;
    f32x4 acc[4][4];
    #pragma unroll
    for (int i = 0; i < 4; i++)
        #pragma unroll
        for (int j = 0; j < 4; j++) acc[i][j] = (f32x4){0.f, 0.f, 0.f, 0.f};

    auto stage = [&](int buf, int kt) {
        const int k0 = koff + kt * 32;
        const unsigned short* ga0;
        if (!CONV) {
            ga0 = A + (size_t)(m0 + sr) * K + k0 + sc;
        } else {
            const int j = k0 / Cch, c0 = k0 - j * Cch;
            ga0 = A + (size_t)(bb * SP + s0 + j + sr) * Cch + c0 + sc;
        }
        const unsigned short* gb0 = W + (size_t)(n0 + sr) * K + k0 + sc;
        const size_t astep = (size_t)16 * (CONV ? Cch : K);
        #pragma unroll
        for (int i = 0; i < 2; i++) {
            gload_lds16(ga0 + i * astep, &Abuf[buf][(wave * 2 + i) * 512]);
            gload_lds16(gb0 + (size_t)i * 16 * K, &Bbuf[buf][(wave * 2 + i) * 512]);
        }
    };

    stage(0, 0);
    __syncthreads();
    int cur = 0;
    for (int kt = 0; kt < NT; ++kt) {
        if (kt + 1 < NT) stage(cur ^ 1, kt + 1);
        short8v af[4], bf[4];
        #pragma unroll
        for (int mi = 0; mi < 4; mi++)
            af[mi] = *reinterpret_cast<const short8v*>(&Abuf[cur][(wm + mi * 16 + lr) * 32 + lg * 8]);
        #pragma unroll
        for (int ni = 0; ni < 4; ni++)
            bf[ni] = *reinterpret_cast<const short8v*>(&Bbuf[cur][(wn + ni * 16 + lr) * 32 + lg * 8]);
        #pragma unroll
        for (int mi = 0; mi < 4; mi++)
            #pragma unroll
            for (int ni = 0; ni < 4; ni++)
                acc[mi][ni] = __builtin_amdgcn_mfma_f32_16x16x32_bf16(af[mi], bf[ni], acc[mi][ni], 0, 0, 0);
        __syncthreads();
        cur ^= 1;
    }

    #pragma unroll
    for (int ni = 0; ni < 4; ni++) {
        const int col = n0 + wn + ni * 16 + lr;
        const float bv = bias ? bias[col] : 0.f;
        #pragma unroll
        for (int mi = 0; mi < 4; mi++)
            #pragma unroll
            for (int r = 0; r < 4; r++)
                C[(size_t)(m0 + wm + mi * 16 + lg * 4 + r) * N + col] = acc[mi][ni][r] + bv;
    }
}

// ---------------- grouped causal conv1 (reads qkv split-K partials p0+p1) ----------------
__global__ __launch_bounds__(256)
void conv1_grouped(const float* __restrict__ qkv0, const float* __restrict__ qkv1, int coloff,
                   const float* __restrict__ w, const float* __restrict__ bias,
                   unsigned short* __restrict__ out, int CH)
{
    const int t0 = blockIdx.x * 64;
    const int b  = blockIdx.y;
    const int g  = blockIdx.z;
    __shared__ float xs[66][64];
    for (int idx = threadIdx.x; idx < 66 * 64; idx += 256) {
        const int i = idx >> 6, ic = idx & 63;
        const int tt = t0 + i - 2;
        float v = 0.f;
        if (tt >= 0) {
            const size_t off = (size_t)(b * SEQ + tt) * QKVN + coloff + g * 64 + ic;
            v = qkv0[off] + qkv1[off];
        }
        xs[i][ic] = v;
    }
    __syncthreads();
    const int oc = threadIdx.x & 63;
    const int ibase = (threadIdx.x >> 6) * 16;
    float acc[16];
    const float bv = bias[g * 64 + oc];
    #pragma unroll
    for (int i = 0; i < 16; i++) acc[i] = bv;
    const float* wp = w + (size_t)(g * 64 + oc) * 192;
    for (int ic = 0; ic < 64; ic++) {
        const float w0 = wp[ic * 3 + 0], w1 = wp[ic * 3 + 1], w2 = wp[ic * 3 + 2];
        float xv[18];
        #pragma unroll
        for (int r = 0; r < 18; r++) xv[r] = xs[ibase + r][ic];
        #pragma unroll
        for (int i = 0; i < 16; i++) acc[i] += w0 * xv[i] + w1 * xv[i + 1] + w2 * xv[i + 2];
    }
    #pragma unroll
    for (int i = 0; i < 16; i++)
        out[((size_t)b * SP + 2 + t0 + ibase + i) * CH + g * 64 + oc] = f2bf(acc[i]);
}

// ---------------- head means + shifted-v build (reads qkv partials p0+p1) ----------------
__global__ __launch_bounds__(64)
void meanv_kernel(const float* __restrict__ qkv0, const float* __restrict__ qkv1,
                  float* __restrict__ qmean, float* __restrict__ kmean,
                  unsigned short* __restrict__ vRow)
{
    const int t = blockIdx.x, d = threadIdx.x;
    const int b = t >> 11, s = t & (SEQ - 1);
    const float* r0 = qkv0 + (size_t)t * QKVN;
    const float* r1 = qkv1 + (size_t)t * QKVN;
    float qs = 0.f;
    #pragma unroll
    for (int h = 0; h < NH; h++) qs += r0[h * 64 + d] + r1[h * 64 + d];
    qmean[t * 64 + d] = qs * (1.f / NH);
    float ks = 0.f;
    #pragma unroll
    for (int h = 0; h < NKV; h++) ks += r0[LATENT + h * 64 + d] + r1[LATENT + h * 64 + d];
    kmean[t * 64 + d] = ks * (1.f / NKV);
    #pragma unroll
    for (int g = 0; g < NKV; g++) {
        const int c = g * 64 + d;
        float v;
        if (c < 128) {
            v = r0[LATENT + KVD + c] + r1[LATENT + KVD + c];
        } else {
            v = 0.f;
            if (s > 0) {
                const size_t off = (size_t)(t - 1) * QKVN + LATENT + KVD + 128 + (c - 128);
                v = qkv0[off] + qkv1[off];
            }
        }
        vRow[((size_t)(b * NKV + g) * SEQ + s) * 64 + d] = f2bf(v);
    }
}

// ---------------- V transpose to d-major: vTb[bg][d][S] ----------------
__global__ __launch_bounds__(256)
void vtrans(const unsigned short* __restrict__ vRow, unsigned short* __restrict__ vTb)
{
    const int s0 = blockIdx.x * 64;
    const int bg = blockIdx.y;
    __shared__ unsigned short t[64][72];
    const int tid = threadIdx.x;
    {
        const int r = tid >> 2, c0 = (tid & 3) * 16;
        const unsigned short* p = vRow + ((size_t)bg * SEQ + s0 + r) * 64 + c0;
        const short8v a = *reinterpret_cast<const short8v*>(p);
        const short8v bv = *reinterpret_cast<const short8v*>(p + 8);
        #pragma unroll
        for (int j = 0; j < 8; j++) { t[r][c0 + j] = (unsigned short)a[j]; t[r][c0 + 8 + j] = (unsigned short)bv[j]; }
    }
    __syncthreads();
    {
        const int d = tid >> 2, ss = (tid & 3) * 16;
        short8v o0, o1;
        #pragma unroll
        for (int j = 0; j < 8; j++) { o0[j] = (short)t[ss + j][d]; o1[j] = (short)t[ss + 8 + j][d]; }
        unsigned short* op = vTb + ((size_t)bg * 64 + d) * SEQ + s0 + ss;
        *reinterpret_cast<short8v*>(op) = o0;
        *reinterpret_cast<short8v*>(op + 8) = o1;
    }
}

// ---------------- fused conv2-partial merge + bias, +0.5*mean, l2norm, rope(table) -> bf16 ----------------
__global__ __launch_bounds__(64)
void qk_final(const float* __restrict__ qc2a, const float* __restrict__ qc2b,
              const float* __restrict__ kc2a, const float* __restrict__ kc2b,
              const float* __restrict__ qbias, const float* __restrict__ kbias,
              const float* __restrict__ qmean, const float* __restrict__ kmean,
              const float* __restrict__ key_temp, const float2* __restrict__ rtab,
              unsigned short* __restrict__ qTb, unsigned short* __restrict__ kTb)
{
    const int t = blockIdx.x, hh = blockIdx.y, d = threadIdx.x;
    const int b = t >> 11, s = t & (SEQ - 1);
    float val;
    if (hh < NH) {
        const size_t off = (size_t)t * LATENT + hh * 64 + d;
        val = qc2a[off] + qc2b[off] + qbias[hh * 64 + d] + 0.5f * kmean[t * 64 + d];
    } else {
        const size_t off = (size_t)t * KVD + (hh - NH) * 64 + d;
        val = kc2a[off] + kc2b[off] + kbias[(hh - NH) * 64 + d] + 0.5f * qmean[t * 64 + d];
    }
    float ss = val * val;
    #pragma unroll
    for (int off = 32; off >= 1; off >>= 1) ss += __shfl_xor(ss, off);
    const float n = sqrtf(ss);
    val = val / fmaxf(n, 1e-12f);
    if (hh >= NH) val *= key_temp[0];
    const float2 cs = rtab[s * 32 + (d >> 1)];
    const float cv = cs.x, sv = cs.y;
    const float partner = __shfl_xor(val, 1);
    const float x1 = (d & 1) ? partner : val;
    const float x2 = (d & 1) ? val : partner;
    const float o = (d & 1) ? (x1 * sv + x2 * cv) : (x1 * cv - x2 * sv);
    if (hh < NH) qTb[((size_t)(b * NH + hh) * SEQ + s) * 64 + d] = f2bf(o);
    else         kTb[((size_t)(b * NKV + (hh - NH)) * SEQ + s) * 64 + d] = f2bf(o);
}

// ---------------- MFMA causal GQA attention: 4-wave block shares K/V via LDS, BK=64 ----------------
__global__ __launch_bounds__(256)
void attn_mfma(const unsigned short* __restrict__ qTb, const unsigned short* __restrict__ kTb,
               const unsigned short* __restrict__ vTb, unsigned short* __restrict__ attn_out)
{
    const int wg = blockIdx.x;
    int bh, blk;
    if (wg < 256) {
        const int xcd = wg & 7, i = wg >> 3;
        bh = (xcd << 2) | (i >> 3);
        blk = 15 - (i & 7);          // 8..15
    } else {
        const int u = wg - 256;
        const int xcd = u & 7, i = u >> 3;
        bh = (xcd << 2) | (i >> 3);
        blk = i & 7;                 // 0..7
    }
    const int b = bh >> 4, h = bh & 15, g = h >> 2;
    const int tid = threadIdx.x;
    const int wave = tid >> 6, lane = tid & 63;
    const int lg = lane >> 4, lr = lane & 15;
    const int qt = blk * 4 + wave;
    const int q0 = qt * 32;
    const int ctot2 = (blk + 1) * 2;     // 64-key phases

    __shared__ __align__(16) unsigned short SB[2][16][512];

    short8v qf[2][2];
    const unsigned short* qbase = qTb + ((size_t)(b * NH + h) * SEQ + q0) * 64;
    #pragma unroll
    for (int mf = 0; mf < 2; mf++)
        #pragma unroll
        for (int dc = 0; dc < 2; dc++)
            qf[mf][dc] = *reinterpret_cast<const short8v*>(qbase + (size_t)(mf * 16 + lr) * 64 + dc * 32 + lg * 8);

    f32x4 acc[2][4];
    float lsum[2] = {0.f, 0.f};
    #pragma unroll
    for (int mf = 0; mf < 2; mf++)
        #pragma unroll
        for (int dt = 0; dt < 4; dt++) acc[mf][dt] = (f32x4){0.f, 0.f, 0.f, 0.f};

    const unsigned short* kbase = kTb + (size_t)(b * NKV + g) * SEQ * 64;
    const unsigned short* vbase = vTb + (size_t)(b * NKV + g) * 64 * SEQ;
    const float EC = 0.125f * 1.44269504f;
    const int src01 = ((lg & 1) << 5) + lr;
    const int src23 = src01 + 16;
    const bool hi = (lg >= 2);

    auto stage64 = [&](int buf, int cc) {
        const int kb = cc * 64;
        #pragma unroll
        for (int i = 0; i < 4; i++) {
            const int ch = wave * 4 + i;
            const int st = ch >> 3, chl = ch & 7;
            const int k0 = kb + st * 32;
            const unsigned short* src;
            if (chl < 4) src = kbase + (size_t)(k0 + (chl >> 1) * 16 + lr) * 64 + (chl & 1) * 32 + lg * 8;
            else         src = vbase + (size_t)((chl - 4) * 16 + lr) * SEQ + k0 + lg * 8;
            gload_lds16(src, &SB[buf][ch][lane * 8]);
        }
    };

    stage64(0, 0);
    __syncthreads();
    int cur = 0;
    for (int cc = 0; cc < ctot2; ++cc) {
        if (cc + 1 < ctot2) stage64(cur ^ 1, cc + 1);
        #pragma unroll
        for (int st = 0; st < 2; ++st) {
            const int c = cc * 2 + st;
            if (c > qt) continue;
            const int k0 = c * 32;
            short8v kf[2][2], vf[4];
            #pragma unroll
            for (int kt = 0; kt < 2; kt++)
                #pragma unroll
                for (int dc = 0; dc < 2; dc++)
                    kf[kt][dc] = *reinterpret_cast<const short8v*>(&SB[cur][st * 8 + kt * 2 + dc][lane * 8]);
            #pragma unroll
            for (int dt = 0; dt < 4; dt++)
                vf[dt] = *reinterpret_cast<const short8v*>(&SB[cur][st * 8 + 4 + dt][lane * 8]);

            const bool diag = (c == qt);
            #pragma unroll
            for (int mf = 0; mf < 2; mf++) {
                f32x4 z0 = (f32x4){0.f, 0.f, 0.f, 0.f}, z1 = (f32x4){0.f, 0.f, 0.f, 0.f};
                __builtin_amdgcn_s_setprio(1);
                z0 = __builtin_amdgcn_mfma_f32_16x16x32_bf16(kf[0][0], qf[mf][0], z0, 0, 0, 0);
                z0 = __builtin_amdgcn_mfma_f32_16x16x32_bf16(kf[0][1], qf[mf][1], z0, 0, 0, 0);
                z1 = __builtin_amdgcn_mfma_f32_16x16x32_bf16(kf[1][0], qf[mf][0], z1, 0, 0, 0);
                z1 = __builtin_amdgcn_mfma_f32_16x16x32_bf16(kf[1][1], qf[mf][1], z1, 0, 0, 0);
                __builtin_amdgcn_s_setprio(0);
                float p0[4], p1[4];
                #pragma unroll
                for (int r = 0; r < 4; r++) {
                    p0[r] = exp2f(z0[r] * EC);
                    p1[r] = exp2f(z1[r] * EC);
                }
                if (diag) {
                    const int q = q0 + mf * 16 + lr;
                    #pragma unroll
                    for (int r = 0; r < 4; r++) {
                        if (k0 + 4 * lg + r > q)      p0[r] = 0.f;
                        if (k0 + 16 + 4 * lg + r > q) p1[r] = 0.f;
                    }
                }
                lsum[mf] += (p0[0] + p0[1]) + (p0[2] + p0[3]) + (p1[0] + p1[1]) + (p1[2] + p1[3]);
                const unsigned W00 = cvt_pk_bf16(p0[0], p0[1]);
                const unsigned W01 = cvt_pk_bf16(p0[2], p0[3]);
                const unsigned W10 = cvt_pk_bf16(p1[0], p1[1]);
                const unsigned W11 = cvt_pk_bf16(p1[2], p1[3]);
                const unsigned a0 = __shfl(W00, src01), b0 = __shfl(W10, src01);
                const unsigned a1 = __shfl(W01, src01), b1 = __shfl(W11, src01);
                const unsigned a2 = __shfl(W00, src23), b2 = __shfl(W10, src23);
                const unsigned a3 = __shfl(W01, src23), b3 = __shfl(W11, src23);
                uint4v pw;
                pw.x = hi ? b0 : a0;
                pw.y = hi ? b1 : a1;
                pw.z = hi ? b2 : a2;
                pw.w = hi ? b3 : a3;
                const short8v pa = __builtin_bit_cast(short8v, pw);
                __builtin_amdgcn_s_setprio(1);
                #pragma unroll
                for (int dt = 0; dt < 4; dt++)
                    acc[mf][dt] = __builtin_amdgcn_mfma_f32_16x16x32_bf16(pa, vf[dt], acc[mf][dt], 0, 0, 0);
                __builtin_amdgcn_s_setprio(0);
            }
        }
        __syncthreads();
        cur ^= 1;
    }

    float den[2];
    #pragma unroll
    for (int mf = 0; mf < 2; mf++) {
        float s = lsum[mf];
        s += __shfl_xor(s, 16); s += __shfl_xor(s, 32);
        den[mf] = s;
    }

    #pragma unroll
    for (int mf = 0; mf < 2; mf++) {
        float dinv[4];
        #pragma unroll
        for (int r = 0; r < 4; r++) dinv[r] = 1.f / __shfl(den[mf], 4 * lg + r);
        #pragma unroll
        for (int dt = 0; dt < 4; dt++)
            #pragma unroll
            for (int r = 0; r < 4; r++) {
                const int q = q0 + mf * 16 + 4 * lg + r;
                attn_out[(size_t)(b * SEQ + q) * LATENT + h * 64 + dt * 16 + lr] = f2bf(acc[mf][dt][r] * dinv[r]);
            }
    }
}

extern "C" void kernel_launch(void* const* d_in, const int* in_sizes, int n_in,
                              void* d_out, int out_size, void* d_ws, size_t ws_size,
                              hipStream_t stream)
{
    const float* x       = (const float*)d_in[0];
    const float* w_qkv   = (const float*)d_in[1];
    const float* w_o     = (const float*)d_in[2];
    const float* qc1_w   = (const float*)d_in[3];
    const float* qc1_b   = (const float*)d_in[4];
    const float* qc2_w   = (const float*)d_in[5];
    const float* qc2_b   = (const float*)d_in[6];
    const float* kc1_w   = (const float*)d_in[7];
    const float* kc1_b   = (const float*)d_in[8];
    const float* kc2_w   = (const float*)d_in[9];
    const float* kc2_b   = (const float*)d_in[10];
    const float* key_temp = (const float*)d_in[11];

    // --- workspace layout (aliased by lifetime; byte offsets noted) ---
    char* wsb = (char*)d_ws;
    float* qkv = (float*)wsb;                 wsb += (size_t)BS * QKVN * 4;     // [0, 25165824)
    float* qc2 = qkv;                                                            // alias (qkv dead after conv1)
    float* kc2 = (float*)((char*)qkv + (size_t)BS * LATENT * 4);                 // [16777216, 20971520)
    unsigned short* pq  = (unsigned short*)wsb;  wsb += (size_t)NB * SP * LATENT * 2;  // [25165824, 33562624)
    unsigned short* pk  = (unsigned short*)wsb;  wsb += (size_t)NB * SP * KVD * 2;     // [33562624, 35661824)
    float* qmean = (float*)wsb;  wsb += (size_t)BS * HD * 4;
    float* kmean = (float*)wsb;  wsb += (size_t)BS * HD * 4;
    unsigned short* qTb  = (unsigned short*)wsb;  wsb += (size_t)BS * LATENT * 2;
    unsigned short* kTb  = (unsigned short*)wsb;  wsb += (size_t)BS * KVD * 2;
    unsigned short* vRow = (unsigned short*)wsb;  wsb += (size_t)BS * KVD * 2;
    unsigned short* vTb  = (unsigned short*)wsb;  wsb += (size_t)BS * KVD * 2;   // ends 52439040
    unsigned short* xb   = (unsigned short*)wsb;  wsb += (size_t)BS * DIMX * 2;  // [52439040, 85993472)
    unsigned short* attnb  = xb;
    unsigned short* qc2wr  = (unsigned short*)((char*)xb + (size_t)BS * LATENT * 2);
    unsigned short* kc2wr  = (unsigned short*)((char*)qc2wr + (size_t)LATENT * LATENT * 3 * 2);
    unsigned short* wqkvb = (unsigned short*)wsb;  wsb += (size_t)QKVN * DIMX * 2;  // [85993472, 98576384)
    unsigned short* wob   = wqkvb;

    float* outp = (float*)d_out;

    // qkv split-K=2: partial z=1 goes to d_out (67MB, dead until final GEMM overwrites it).
    // No region of d_ws is lifetime-free for it (meanv/conv1 consumers overlap everything).
    float* qkvp1 = outp;
    const size_t QKV_PS = (size_t)((ptrdiff_t)(qkvp1 - qkv));   // modular arithmetic: qkv + PS == outp
    // conv2 partials (dead regions in stream order at their GEMM's position):
    float* qc2p1 = (float*)((char*)d_ws + 67512320);              // xb tail (dead), 16.7MB
    float* kc2p1 = (float*)((char*)d_ws + (size_t)BS * QKVN * 4); // pq region (dead after conv2-q GEMM)
    const size_t QC2_PS = (size_t)(qc2p1 - qc2);
    const size_t KC2_PS = (size_t)(kc2p1 - kc2);
    float2* rtab = (float2*)vRow;   // rope table in dead vRow region

    // 1. casts for qkv GEMM
    cast_f2b<<<dim3(BS * DIMX / 4 / 256), 256, 0, stream>>>(x, xb, BS * DIMX / 4);
    cast_f2b<<<dim3(QKVN * DIMX / 4 / 256), 256, 0, stream>>>(w_qkv, wqkvb, QKVN * DIMX / 4);
    // 2. qkv projection, split-K=2 (768 blocks); partials merged by consumers (no add2)
    gemm_bf16<0><<<dim3(QKVN / 128, BS / 128, 2), 256, 0, stream>>>(xb, wqkvb, nullptr, qkv, BS, QKVN, DIMX, 0, DIMX / 2, QKV_PS);
    // 3. prep for later GEMMs (xb/wqkvb dead after their consumers below)
    cast_f2b<<<dim3(DIMX * LATENT / 4 / 256), 256, 0, stream>>>(w_o, wob, DIMX * LATENT / 4);
    w3reorder<<<dim3((LATENT * LATENT * 3 + 255) / 256), 256, 0, stream>>>(qc2_w, qc2wr, LATENT, LATENT);
    w3reorder<<<dim3((KVD * KVD * 3 + 255) / 256), 256, 0, stream>>>(kc2_w, kc2wr, KVD, KVD);
    // 4. means + shifted v (merging qkv partials), V transpose, rope table, pads
    meanv_kernel<<<dim3(BS), 64, 0, stream>>>(qkv, qkvp1, qmean, kmean, vRow);
    vtrans<<<dim3(SEQ / 64, NB * NKV), 256, 0, stream>>>(vRow, vTb);
    rope_tab<<<dim3(SEQ * 32 / 256), 256, 0, stream>>>(rtab);
    zero_pad<<<dim3(16), 256, 0, stream>>>(pq, pk);
    // 5. grouped conv1 (merging qkv partials) -> padded bf16
    conv1_grouped<<<dim3(SEQ / 64, NB, NH),  256, 0, stream>>>(qkv, qkvp1, 0,      qc1_w, qc1_b, pq, LATENT);
    conv1_grouped<<<dim3(SEQ / 64, NB, NKV), 256, 0, stream>>>(qkv, qkvp1, LATENT, kc1_w, kc1_b, pk, KVD);
    // 6. conv2 as split-K bf16 GEMMs; partials merged inside qk_final
    gemm_bf16<1><<<dim3(LATENT / 128, BS / 128, 2), 256, 0, stream>>>(pq, qc2wr, nullptr, qc2, BS, LATENT, LATENT * 3, LATENT, LATENT * 3 / 2, QC2_PS);
    gemm_bf16<1><<<dim3(KVD / 128, BS / 128, 2), 256, 0, stream>>>(pk, kc2wr, nullptr, kc2, BS, KVD, KVD * 3, KVD, KVD * 3 / 2, KC2_PS);
    // 7. fused merge+bias, +0.5*mean, l2norm, rope
    qk_final<<<dim3(BS, NH + NKV), 64, 0, stream>>>(qc2, qc2p1, kc2, kc2p1, qc2_b, kc2_b,
                                                    qmean, kmean, key_temp, rtab, qTb, kTb);
    // 8. attention (work-balanced pairing, BK=64)
    attn_mfma<<<dim3(512), 256, 0, stream>>>(qTb, kTb, vTb, attnb);
    // 9. output projection (1024 blocks, 4/CU) -- overwrites all of d_out
    gemm_bf16<0><<<dim3(DIMX / 128, BS / 128, 1), 256, 0, stream>>>(attnb, wob, nullptr, outp, BS, DIMX, LATENT, 0, LATENT, 0);
}

// Round 14
// 356.369 us; speedup vs baseline: 1.1137x; 1.0598x over previous
//
#include <hip/hip_runtime.h>
#include <hip/hip_bf16.h>
#include <cstddef>

#define NB 2
#define SEQ 2048
#define DIMX 4096
#define NH 16
#define NKV 4
#define HD 64
#define LATENT 1024
#define KVD 256
#define QKVN 1536
#define BS (NB*SEQ)
#define SP (SEQ+2)   // padded token rows per batch for conv2 input

typedef __attribute__((ext_vector_type(8))) short short8v;   // 8 bf16 = 4 VGPR
typedef __attribute__((ext_vector_type(4))) float f32x4;
typedef __attribute__((ext_vector_type(4))) unsigned short ushort4v;
typedef __attribute__((ext_vector_type(4))) unsigned int uint4v;

static __device__ __forceinline__ unsigned short f2bf(float f) {
    union { float f; unsigned u; } v; v.f = f;
    unsigned r = v.u + 0x7fffu + ((v.u >> 16) & 1u);
    return (unsigned short)(r >> 16);
}

static __device__ __forceinline__ unsigned cvt_pk_bf16(float lo, float hi) {
    unsigned r;
    asm("v_cvt_pk_bf16_f32 %0, %1, %2" : "=v"(r) : "v"(lo), "v"(hi));
    return r;
}

static __device__ __forceinline__ void gload_lds16(const unsigned short* g, unsigned short* l) {
    __builtin_amdgcn_global_load_lds((const __attribute__((address_space(1))) void*)g,
                                     (__attribute__((address_space(3))) void*)l, 16, 0, 0);
}

// ---------------- fp32 -> bf16 cast (vectorized x4) ----------------
__global__ __launch_bounds__(256)
void cast_f2b(const float* __restrict__ in, unsigned short* __restrict__ out, int n4)
{
    const int i = blockIdx.x * 256 + threadIdx.x;
    if (i < n4) {
        const float4 v = *reinterpret_cast<const float4*>(in + (size_t)i * 4);
        ushort4v o = {f2bf(v.x), f2bf(v.y), f2bf(v.z), f2bf(v.w)};
        *reinterpret_cast<ushort4v*>(out + (size_t)i * 4) = o;
    }
}

// ---------------- fused prep: w_o cast | qc2w reorder | kc2w reorder | rope table | zero pads ----------------
#define WO_BLK 4096    // DIMX*LATENT/4/256
#define QW_N (LATENT*LATENT*3)
#define QW_BLK 12288
#define KW_N (KVD*KVD*3)
#define KW_BLK 768
#define RT_BLK 256     // SEQ*32/256
__global__ __launch_bounds__(256)
void prep_misc(const float* __restrict__ wo, unsigned short* __restrict__ wob,
               const float* __restrict__ qc2w, unsigned short* __restrict__ qc2wr,
               const float* __restrict__ kc2w, unsigned short* __restrict__ kc2wr,
               float2* __restrict__ rtab,
               unsigned short* __restrict__ pq, unsigned short* __restrict__ pk)
{
    const int blk = blockIdx.x, tid = threadIdx.x;
    if (blk < WO_BLK) {
        const int i = blk * 256 + tid;
        const float4 v = *reinterpret_cast<const float4*>(wo + (size_t)i * 4);
        ushort4v o = {f2bf(v.x), f2bf(v.y), f2bf(v.z), f2bf(v.w)};
        *reinterpret_cast<ushort4v*>(wob + (size_t)i * 4) = o;
    } else if (blk < WO_BLK + QW_BLK) {
        const int idx = (blk - WO_BLK) * 256 + tid;
        if (idx < QW_N) {
            const int o = idx / (LATENT * 3), rem = idx % (LATENT * 3);
            const int j = rem / LATENT, c = rem % LATENT;
            qc2wr[idx] = f2bf(qc2w[(size_t)o * LATENT * 3 + c * 3 + j]);
        }
    } else if (blk < WO_BLK + QW_BLK + KW_BLK) {
        const int idx = (blk - WO_BLK - QW_BLK) * 256 + tid;
        if (idx < KW_N) {
            const int o = idx / (KVD * 3), rem = idx % (KVD * 3);
            const int j = rem / KVD, c = rem % KVD;
            kc2wr[idx] = f2bf(kc2w[(size_t)o * KVD * 3 + c * 3 + j]);
        }
    } else if (blk < WO_BLK + QW_BLK + KW_BLK + RT_BLK) {
        const int idx = (blk - WO_BLK - QW_BLK - KW_BLK) * 256 + tid;
        const int s = idx >> 5, i = idx & 31;
        const float inv = powf(10000.f, -(float)(2 * i) * (1.f / HD));
        const float ang = (float)s * inv;
        rtab[idx] = make_float2(cosf(ang), sinf(ang));
    } else {
        const int t = (blk - WO_BLK - QW_BLK - KW_BLK - RT_BLK) * 256 + tid;
        if (t < 2 * 2 * LATENT) {
            const int b = t / (2 * LATENT), r = (t % (2 * LATENT)) / LATENT, c = t % LATENT;
            pq[((size_t)b * SP + r) * LATENT + c] = 0;
        }
        if (t < 2 * 2 * KVD) {
            const int b = t / (2 * KVD), r = (t % (2 * KVD)) / KVD, c = t % KVD;
            pk[((size_t)b * SP + r) * KVD + c] = 0;
        }
    }
}

// ---------------- bf16 MFMA GEMM: C[M][N] = A[M][K] @ W[N][K]^T, fp32 out ----------------
// 128x128 tile, BK=32, 2-phase double-buffered global_load_lds staging, split-K via grid.z.
template<int CONV>
__global__ __launch_bounds__(256)
void gemm_bf16(const unsigned short* __restrict__ A, const unsigned short* __restrict__ W,
               const float* __restrict__ bias, float* __restrict__ C,
               int M, int N, int K, int Cch, int klen, size_t pstride)
{
    __shared__ unsigned short Abuf[2][128 * 32];
    __shared__ unsigned short Bbuf[2][128 * 32];
    const int gx = gridDim.x;
    const int nwg = gx * gridDim.y;
    const int lin = blockIdx.y * gx + blockIdx.x;
    const int swz = (lin & 7) * (nwg >> 3) + (lin >> 3);
    const int n0 = (swz % gx) * 128, m0 = (swz / gx) * 128;
    const int koff = blockIdx.z * klen;
    C += (size_t)blockIdx.z * pstride;
    const int tid = threadIdx.x;
    const int wave = tid >> 6, lane = tid & 63;
    const int lg = lane >> 4, lr = lane & 15;
    const int wm = (wave & 1) * 64, wn = (wave >> 1) * 64;
    const int sr = wave * 32 + (lane >> 2);
    const int sc = (lane & 3) * 8;
    const int bb = m0 / SEQ, s0 = m0 % SEQ;

    const int NT = klen / 32;
    f32x4 acc[4][4];
    #pragma unroll
    for (int i = 0; i < 4; i++)
        #pragma unroll
        for (int j = 0; j < 4; j++) acc[i][j] = (f32x4){0.f, 0.f, 0.f, 0.f};

    auto stage = [&](int buf, int kt) {
        const int k0 = koff + kt * 32;
        const unsigned short* ga0;
        if (!CONV) {
            ga0 = A + (size_t)(m0 + sr) * K + k0 + sc;
        } else {
            const int j = k0 / Cch, c0 = k0 - j * Cch;
            ga0 = A + (size_t)(bb * SP + s0 + j + sr) * Cch + c0 + sc;
        }
        const unsigned short* gb0 = W + (size_t)(n0 + sr) * K + k0 + sc;
        const size_t astep = (size_t)16 * (CONV ? Cch : K);
        #pragma unroll
        for (int i = 0; i < 2; i++) {
            gload_lds16(ga0 + i * astep, &Abuf[buf][(wave * 2 + i) * 512]);
            gload_lds16(gb0 + (size_t)i * 16 * K, &Bbuf[buf][(wave * 2 + i) * 512]);
        }
    };

    stage(0, 0);
    __syncthreads();
    int cur = 0;
    for (int kt = 0; kt < NT; ++kt) {
        if (kt + 1 < NT) stage(cur ^ 1, kt + 1);
        short8v af[4], bf[4];
        #pragma unroll
        for (int mi = 0; mi < 4; mi++)
            af[mi] = *reinterpret_cast<const short8v*>(&Abuf[cur][(wm + mi * 16 + lr) * 32 + lg * 8]);
        #pragma unroll
        for (int ni = 0; ni < 4; ni++)
            bf[ni] = *reinterpret_cast<const short8v*>(&Bbuf[cur][(wn + ni * 16 + lr) * 32 + lg * 8]);
        #pragma unroll
        for (int mi = 0; mi < 4; mi++)
            #pragma unroll
            for (int ni = 0; ni < 4; ni++)
                acc[mi][ni] = __builtin_amdgcn_mfma_f32_16x16x32_bf16(af[mi], bf[ni], acc[mi][ni], 0, 0, 0);
        __syncthreads();
        cur ^= 1;
    }

    #pragma unroll
    for (int ni = 0; ni < 4; ni++) {
        const int col = n0 + wn + ni * 16 + lr;
        const float bv = bias ? bias[col] : 0.f;
        #pragma unroll
        for (int mi = 0; mi < 4; mi++)
            #pragma unroll
            for (int r = 0; r < 4; r++)
                C[(size_t)(m0 + wm + mi * 16 + lg * 4 + r) * N + col] = acc[mi][ni][r] + bv;
    }
}

// ---------------- grouped causal conv1 (reads qkv split-K partials p0+p1) ----------------
__global__ __launch_bounds__(256)
void conv1_grouped(const float* __restrict__ qkv0, const float* __restrict__ qkv1, int coloff,
                   const float* __restrict__ w, const float* __restrict__ bias,
                   unsigned short* __restrict__ out, int CH)
{
    const int t0 = blockIdx.x * 64;
    const int b  = blockIdx.y;
    const int g  = blockIdx.z;
    __shared__ float xs[66][64];
    for (int idx = threadIdx.x; idx < 66 * 64; idx += 256) {
        const int i = idx >> 6, ic = idx & 63;
        const int tt = t0 + i - 2;
        float v = 0.f;
        if (tt >= 0) {
            const size_t off = (size_t)(b * SEQ + tt) * QKVN + coloff + g * 64 + ic;
            v = qkv0[off] + qkv1[off];
        }
        xs[i][ic] = v;
    }
    __syncthreads();
    const int oc = threadIdx.x & 63;
    const int ibase = (threadIdx.x >> 6) * 16;
    float acc[16];
    const float bv = bias[g * 64 + oc];
    #pragma unroll
    for (int i = 0; i < 16; i++) acc[i] = bv;
    const float* wp = w + (size_t)(g * 64 + oc) * 192;
    for (int ic = 0; ic < 64; ic++) {
        const float w0 = wp[ic * 3 + 0], w1 = wp[ic * 3 + 1], w2 = wp[ic * 3 + 2];
        float xv[18];
        #pragma unroll
        for (int r = 0; r < 18; r++) xv[r] = xs[ibase + r][ic];
        #pragma unroll
        for (int i = 0; i < 16; i++) acc[i] += w0 * xv[i] + w1 * xv[i + 1] + w2 * xv[i + 2];
    }
    #pragma unroll
    for (int i = 0; i < 16; i++)
        out[((size_t)b * SP + 2 + t0 + ibase + i) * CH + g * 64 + oc] = f2bf(acc[i]);
}

// ---------------- head means + shifted-v build (reads qkv partials p0+p1) ----------------
__global__ __launch_bounds__(64)
void meanv_kernel(const float* __restrict__ qkv0, const float* __restrict__ qkv1,
                  float* __restrict__ qmean, float* __restrict__ kmean,
                  unsigned short* __restrict__ vRow)
{
    const int t = blockIdx.x, d = threadIdx.x;
    const int b = t >> 11, s = t & (SEQ - 1);
    const float* r0 = qkv0 + (size_t)t * QKVN;
    const float* r1 = qkv1 + (size_t)t * QKVN;
    float qs = 0.f;
    #pragma unroll
    for (int h = 0; h < NH; h++) qs += r0[h * 64 + d] + r1[h * 64 + d];
    qmean[t * 64 + d] = qs * (1.f / NH);
    float ks = 0.f;
    #pragma unroll
    for (int h = 0; h < NKV; h++) ks += r0[LATENT + h * 64 + d] + r1[LATENT + h * 64 + d];
    kmean[t * 64 + d] = ks * (1.f / NKV);
    #pragma unroll
    for (int g = 0; g < NKV; g++) {
        const int c = g * 64 + d;
        float v;
        if (c < 128) {
            v = r0[LATENT + KVD + c] + r1[LATENT + KVD + c];
        } else {
            v = 0.f;
            if (s > 0) {
                const size_t off = (size_t)(t - 1) * QKVN + LATENT + KVD + 128 + (c - 128);
                v = qkv0[off] + qkv1[off];
            }
        }
        vRow[((size_t)(b * NKV + g) * SEQ + s) * 64 + d] = f2bf(v);
    }
}

// ---------------- V transpose to d-major: vTb[bg][d][S] ----------------
__global__ __launch_bounds__(256)
void vtrans(const unsigned short* __restrict__ vRow, unsigned short* __restrict__ vTb)
{
    const int s0 = blockIdx.x * 64;
    const int bg = blockIdx.y;
    __shared__ unsigned short t[64][72];
    const int tid = threadIdx.x;
    {
        const int r = tid >> 2, c0 = (tid & 3) * 16;
        const unsigned short* p = vRow + ((size_t)bg * SEQ + s0 + r) * 64 + c0;
        const short8v a = *reinterpret_cast<const short8v*>(p);
        const short8v bv = *reinterpret_cast<const short8v*>(p + 8);
        #pragma unroll
        for (int j = 0; j < 8; j++) { t[r][c0 + j] = (unsigned short)a[j]; t[r][c0 + 8 + j] = (unsigned short)bv[j]; }
    }
    __syncthreads();
    {
        const int d = tid >> 2, ss = (tid & 3) * 16;
        short8v o0, o1;
        #pragma unroll
        for (int j = 0; j < 8; j++) { o0[j] = (short)t[ss + j][d]; o1[j] = (short)t[ss + 8 + j][d]; }
        unsigned short* op = vTb + ((size_t)bg * 64 + d) * SEQ + s0 + ss;
        *reinterpret_cast<short8v*>(op) = o0;
        *reinterpret_cast<short8v*>(op + 8) = o1;
    }
}

// ---------------- fused conv2-partial merge + bias, +0.5*mean, l2norm, rope(table) -> bf16 ----------------
__global__ __launch_bounds__(64)
void qk_final(const float* __restrict__ qc2a, const float* __restrict__ qc2b,
              const float* __restrict__ kc2a, const float* __restrict__ kc2b,
              const float* __restrict__ qbias, const float* __restrict__ kbias,
              const float* __restrict__ qmean, const float* __restrict__ kmean,
              const float* __restrict__ key_temp, const float2* __restrict__ rtab,
              unsigned short* __restrict__ qTb, unsigned short* __restrict__ kTb)
{
    const int t = blockIdx.x, hh = blockIdx.y, d = threadIdx.x;
    const int b = t >> 11, s = t & (SEQ - 1);
    float val;
    if (hh < NH) {
        const size_t off = (size_t)t * LATENT + hh * 64 + d;
        val = qc2a[off] + qc2b[off] + qbias[hh * 64 + d] + 0.5f * kmean[t * 64 + d];
    } else {
        const size_t off = (size_t)t * KVD + (hh - NH) * 64 + d;
        val = kc2a[off] + kc2b[off] + kbias[(hh - NH) * 64 + d] + 0.5f * qmean[t * 64 + d];
    }
    float ss = val * val;
    #pragma unroll
    for (int off = 32; off >= 1; off >>= 1) ss += __shfl_xor(ss, off);
    const float n = sqrtf(ss);
    val = val / fmaxf(n, 1e-12f);
    if (hh >= NH) val *= key_temp[0];
    const float2 cs = rtab[s * 32 + (d >> 1)];
    const float cv = cs.x, sv = cs.y;
    const float partner = __shfl_xor(val, 1);
    const float x1 = (d & 1) ? partner : val;
    const float x2 = (d & 1) ? val : partner;
    const float o = (d & 1) ? (x1 * sv + x2 * cv) : (x1 * cv - x2 * sv);
    if (hh < NH) qTb[((size_t)(b * NH + hh) * SEQ + s) * 64 + d] = f2bf(o);
    else         kTb[((size_t)(b * NKV + (hh - NH)) * SEQ + s) * 64 + d] = f2bf(o);
}

// ---------------- MFMA causal GQA attention: key-split x2, 4-wave shared staging, BK=64 ----------------
// Each (bh,blk) is split into part 0/1, each walking half=(blk+1) of the 2*(blk+1) 64-key phases.
// 1024 blocks (4/CU); rank-complementary map gives each CU 4 blocks summing 34 phases.
// Partials (num bf16 [32][64], den f32 [32]) per (bh,qt,part); attn_merge normalizes.
__global__ __launch_bounds__(256)
void attn_mfma(const unsigned short* __restrict__ qTb, const unsigned short* __restrict__ kTb,
               const unsigned short* __restrict__ vTb,
               unsigned short* __restrict__ pnum, float* __restrict__ pden)
{
    const int wg = blockIdx.x;
    const int qg = wg >> 8;             // quartile 0..3
    const int u = wg & 255;
    const int xcd = u & 7, i = u >> 3;
    const int bh = (xcd << 2) | (i >> 3);
    const int r = i & 7;
    const int p = (qg == 0) ? r : (qg == 1) ? (15 - r) : (qg == 2) ? (16 + r) : (31 - r);
    const int blk = 15 - (p >> 1);
    const int part = p & 1;
    const int half = blk + 1;           // phases per part
    const int cbeg = part * half, cend = cbeg + half;

    const int b = bh >> 4, h = bh & 15, g = h >> 2;
    const int tid = threadIdx.x;
    const int wave = tid >> 6, lane = tid & 63;
    const int lg = lane >> 4, lr = lane & 15;
    const int qt = blk * 4 + wave;
    const int q0 = qt * 32;

    __shared__ __align__(16) unsigned short SB[2][16][512];

    short8v qf[2][2];
    const unsigned short* qbase = qTb + ((size_t)(b * NH + h) * SEQ + q0) * 64;
    #pragma unroll
    for (int mf = 0; mf < 2; mf++)
        #pragma unroll
        for (int dc = 0; dc < 2; dc++)
            qf[mf][dc] = *reinterpret_cast<const short8v*>(qbase + (size_t)(mf * 16 + lr) * 64 + dc * 32 + lg * 8);

    f32x4 acc[2][4];
    float lsum[2] = {0.f, 0.f};
    #pragma unroll
    for (int mf = 0; mf < 2; mf++)
        #pragma unroll
        for (int dt = 0; dt < 4; dt++) acc[mf][dt] = (f32x4){0.f, 0.f, 0.f, 0.f};

    const unsigned short* kbase = kTb + (size_t)(b * NKV + g) * SEQ * 64;
    const unsigned short* vbase = vTb + (size_t)(b * NKV + g) * 64 * SEQ;
    const float EC = 0.125f * 1.44269504f;
    const int src01 = ((lg & 1) << 5) + lr;
    const int src23 = src01 + 16;
    const bool hi = (lg >= 2);

    auto stage64 = [&](int buf, int cc) {
        const int kb = cc * 64;
        #pragma unroll
        for (int i2 = 0; i2 < 4; i2++) {
            const int ch = wave * 4 + i2;
            const int st = ch >> 3, chl = ch & 7;
            const int k0 = kb + st * 32;
            const unsigned short* src;
            if (chl < 4) src = kbase + (size_t)(k0 + (chl >> 1) * 16 + lr) * 64 + (chl & 1) * 32 + lg * 8;
            else         src = vbase + (size_t)((chl - 4) * 16 + lr) * SEQ + k0 + lg * 8;
            gload_lds16(src, &SB[buf][ch][lane * 8]);
        }
    };

    stage64(0, cbeg);
    __syncthreads();
    int cur = 0;
    for (int cc = cbeg; cc < cend; ++cc) {
        if (cc + 1 < cend) stage64(cur ^ 1, cc + 1);
        #pragma unroll
        for (int st = 0; st < 2; ++st) {
            const int c = cc * 2 + st;
            if (c > qt) continue;
            const int k0 = c * 32;
            short8v kf[2][2], vf[4];
            #pragma unroll
            for (int kt = 0; kt < 2; kt++)
                #pragma unroll
                for (int dc = 0; dc < 2; dc++)
                    kf[kt][dc] = *reinterpret_cast<const short8v*>(&SB[cur][st * 8 + kt * 2 + dc][lane * 8]);
            #pragma unroll
            for (int dt = 0; dt < 4; dt++)
                vf[dt] = *reinterpret_cast<const short8v*>(&SB[cur][st * 8 + 4 + dt][lane * 8]);

            const bool diag = (c == qt);
            #pragma unroll
            for (int mf = 0; mf < 2; mf++) {
                f32x4 z0 = (f32x4){0.f, 0.f, 0.f, 0.f}, z1 = (f32x4){0.f, 0.f, 0.f, 0.f};
                __builtin_amdgcn_s_setprio(1);
                z0 = __builtin_amdgcn_mfma_f32_16x16x32_bf16(kf[0][0], qf[mf][0], z0, 0, 0, 0);
                z0 = __builtin_amdgcn_mfma_f32_16x16x32_bf16(kf[0][1], qf[mf][1], z0, 0, 0, 0);
                z1 = __builtin_amdgcn_mfma_f32_16x16x32_bf16(kf[1][0], qf[mf][0], z1, 0, 0, 0);
                z1 = __builtin_amdgcn_mfma_f32_16x16x32_bf16(kf[1][1], qf[mf][1], z1, 0, 0, 0);
                __builtin_amdgcn_s_setprio(0);
                float p0[4], p1[4];
                #pragma unroll
                for (int rr = 0; rr < 4; rr++) {
                    p0[rr] = exp2f(z0[rr] * EC);
                    p1[rr] = exp2f(z1[rr] * EC);
                }
                if (diag) {
                    const int q = q0 + mf * 16 + lr;
                    #pragma unroll
                    for (int rr = 0; rr < 4; rr++) {
                        if (k0 + 4 * lg + rr > q)      p0[rr] = 0.f;
                        if (k0 + 16 + 4 * lg + rr > q) p1[rr] = 0.f;
                    }
                }
                lsum[mf] += (p0[0] + p0[1]) + (p0[2] + p0[3]) + (p1[0] + p1[1]) + (p1[2] + p1[3]);
                const unsigned W00 = cvt_pk_bf16(p0[0], p0[1]);
                const unsigned W01 = cvt_pk_bf16(p0[2], p0[3]);
                const unsigned W10 = cvt_pk_bf16(p1[0], p1[1]);
                const unsigned W11 = cvt_pk_bf16(p1[2], p1[3]);
                const unsigned a0 = __shfl(W00, src01), b0 = __shfl(W10, src01);
                const unsigned a1 = __shfl(W01, src01), b1 = __shfl(W11, src01);
                const unsigned a2 = __shfl(W00, src23), b2 = __shfl(W10, src23);
                const unsigned a3 = __shfl(W01, src23), b3 = __shfl(W11, src23);
                uint4v pw;
                pw.x = hi ? b0 : a0;
                pw.y = hi ? b1 : a1;
                pw.z = hi ? b2 : a2;
                pw.w = hi ? b3 : a3;
                const short8v pa = __builtin_bit_cast(short8v, pw);
                __builtin_amdgcn_s_setprio(1);
                #pragma unroll
                for (int dt = 0; dt < 4; dt++)
                    acc[mf][dt] = __builtin_amdgcn_mfma_f32_16x16x32_bf16(pa, vf[dt], acc[mf][dt], 0, 0, 0);
                __builtin_amdgcn_s_setprio(0);
            }
        }
        __syncthreads();
        cur ^= 1;
    }

    // partial denominators for this key range: sum over the 4 lane-groups
    float den[2];
    #pragma unroll
    for (int mf = 0; mf < 2; mf++) {
        float s = lsum[mf];
        s += __shfl_xor(s, 16); s += __shfl_xor(s, 32);
        den[mf] = s;
    }

    const int base = ((bh * 64 + qt) * 2 + part);
    if (lg == 0) {
        pden[base * 32 + lr] = den[0];
        pden[base * 32 + 16 + lr] = den[1];
    }
    unsigned short* np = pnum + (size_t)base * 2048;
    #pragma unroll
    for (int mf = 0; mf < 2; mf++)
        #pragma unroll
        for (int dt = 0; dt < 4; dt++)
            #pragma unroll
            for (int rr = 0; rr < 4; rr++)
                np[(mf * 16 + 4 * lg + rr) * 64 + dt * 16 + lr] = f2bf(acc[mf][dt][rr]);
}

// ---------------- merge key-split partials -> bf16 attn output ----------------
__global__ __launch_bounds__(256)
void attn_merge(const unsigned short* __restrict__ pnum, const float* __restrict__ pden,
                unsigned short* __restrict__ attnb)
{
    const int idx = blockIdx.x * 256 + threadIdx.x;   // 524288
    const int d0 = (idx & 7) * 8;
    const int qr = (idx >> 3) & 31;
    const int qt = (idx >> 8) & 63;
    const int bh = idx >> 14;
    const int base = (bh * 64 + qt) * 2;
    const float den = pden[base * 32 + qr] + pden[(base + 1) * 32 + qr];
    const float inv = 1.f / den;
    const short8v n0 = *reinterpret_cast<const short8v*>(pnum + (size_t)base * 2048 + qr * 64 + d0);
    const short8v n1 = *reinterpret_cast<const short8v*>(pnum + (size_t)(base + 1) * 2048 + qr * 64 + d0);
    short8v ov;
    #pragma unroll
    for (int j = 0; j < 8; j++) {
        union { unsigned u; float f; } t0, t1;
        t0.u = ((unsigned)(unsigned short)n0[j]) << 16;
        t1.u = ((unsigned)(unsigned short)n1[j]) << 16;
        ov[j] = (short)f2bf((t0.f + t1.f) * inv);
    }
    const int q = qt * 32 + qr;
    const int b = bh >> 4, h = bh & 15;
    *reinterpret_cast<short8v*>(attnb + (size_t)(b * SEQ + q) * LATENT + h * 64 + d0) = ov;
}

extern "C" void kernel_launch(void* const* d_in, const int* in_sizes, int n_in,
                              void* d_out, int out_size, void* d_ws, size_t ws_size,
                              hipStream_t stream)
{
    const float* x       = (const float*)d_in[0];
    const float* w_qkv   = (const float*)d_in[1];
    const float* w_o     = (const float*)d_in[2];
    const float* qc1_w   = (const float*)d_in[3];
    const float* qc1_b   = (const float*)d_in[4];
    const float* qc2_w   = (const float*)d_in[5];
    const float* qc2_b   = (const float*)d_in[6];
    const float* kc1_w   = (const float*)d_in[7];
    const float* kc1_b   = (const float*)d_in[8];
    const float* kc2_w   = (const float*)d_in[9];
    const float* kc2_b   = (const float*)d_in[10];
    const float* key_temp = (const float*)d_in[11];

    // --- workspace layout (aliased by lifetime; byte offsets noted) ---
    char* wsb = (char*)d_ws;
    float* qkv = (float*)wsb;                 wsb += (size_t)BS * QKVN * 4;     // [0, 25165824)
    float* qc2 = qkv;                                                            // alias (qkv dead after conv1)
    float* kc2 = (float*)((char*)qkv + (size_t)BS * LATENT * 4);                 // [16777216, 20971520)
    unsigned short* pq  = (unsigned short*)wsb;  wsb += (size_t)NB * SP * LATENT * 2;  // [25165824, 33562624)
    unsigned short* pk  = (unsigned short*)wsb;  wsb += (size_t)NB * SP * KVD * 2;     // [33562624, 35661824)
    float* qmean = (float*)wsb;  wsb += (size_t)BS * HD * 4;
    float* kmean = (float*)wsb;  wsb += (size_t)BS * HD * 4;
    unsigned short* qTb  = (unsigned short*)wsb;  wsb += (size_t)BS * LATENT * 2;
    unsigned short* kTb  = (unsigned short*)wsb;  wsb += (size_t)BS * KVD * 2;
    unsigned short* vRow = (unsigned short*)wsb;  wsb += (size_t)BS * KVD * 2;
    unsigned short* vTb  = (unsigned short*)wsb;  wsb += (size_t)BS * KVD * 2;   // ends 52439040
    unsigned short* xb   = (unsigned short*)wsb;  wsb += (size_t)BS * DIMX * 2;  // [52439040, 85993472)
    unsigned short* attnb  = xb;
    unsigned short* qc2wr  = (unsigned short*)((char*)xb + (size_t)BS * LATENT * 2);
    unsigned short* kc2wr  = (unsigned short*)((char*)qc2wr + (size_t)LATENT * LATENT * 3 * 2);
    unsigned short* wqkvb = (unsigned short*)wsb;  wsb += (size_t)QKVN * DIMX * 2;  // [85993472, 98576384)
    unsigned short* wob   = wqkvb;

    float* outp = (float*)d_out;

    // qkv split-K=2: partial z=1 in d_out (dead until final GEMM overwrites it fully)
    float* qkvp1 = outp;
    const size_t QKV_PS = (size_t)((ptrdiff_t)(qkvp1 - qkv));
    // conv2 partials (dead regions in stream order at their GEMM's position):
    float* qc2p1 = (float*)((char*)d_ws + 67512320);              // xb tail, ends 84289536
    float* kc2p1 = (float*)((char*)d_ws + (size_t)BS * QKVN * 4); // pq region (dead after conv2-q GEMM)
    const size_t QC2_PS = (size_t)(qc2p1 - qc2);
    const size_t KC2_PS = (size_t)(kc2p1 - kc2);
    // rope table: free gap [84289536, 85993472) in xb (cast-x dead after qkv GEMM; beyond qc2p1)
    float2* rtab = (float2*)((char*)d_ws + 84289536);             // 512KB
    // attention key-split partials: dead qc2/kc2/pq region after qk_final
    unsigned short* apnum = (unsigned short*)d_ws;                // 16.8MB  [0, 16777216)
    float* apden = (float*)((char*)d_ws + 16777216);              // 0.5MB   [16777216, 17301504)

    // 1. casts for qkv GEMM
    cast_f2b<<<dim3(BS * DIMX / 4 / 256), 256, 0, stream>>>(x, xb, BS * DIMX / 4);
    cast_f2b<<<dim3(QKVN * DIMX / 4 / 256), 256, 0, stream>>>(w_qkv, wqkvb, QKVN * DIMX / 4);
    // 2. qkv projection, split-K=2 (768 blocks); partials merged by consumers
    gemm_bf16<0><<<dim3(QKVN / 128, BS / 128, 2), 256, 0, stream>>>(xb, wqkvb, nullptr, qkv, BS, QKVN, DIMX, 0, DIMX / 2, QKV_PS);
    // 3. fused prep (w_o cast, conv2 weight reorders, rope table, conv pads)
    prep_misc<<<dim3(WO_BLK + QW_BLK + KW_BLK + RT_BLK + 16), 256, 0, stream>>>(
        w_o, wob, qc2_w, qc2wr, kc2_w, kc2wr, rtab, pq, pk);
    // 4. means + shifted v (merging qkv partials), V transpose
    meanv_kernel<<<dim3(BS), 64, 0, stream>>>(qkv, qkvp1, qmean, kmean, vRow);
    vtrans<<<dim3(SEQ / 64, NB * NKV), 256, 0, stream>>>(vRow, vTb);
    // 5. grouped conv1 (merging qkv partials) -> padded bf16
    conv1_grouped<<<dim3(SEQ / 64, NB, NH),  256, 0, stream>>>(qkv, qkvp1, 0,      qc1_w, qc1_b, pq, LATENT);
    conv1_grouped<<<dim3(SEQ / 64, NB, NKV), 256, 0, stream>>>(qkv, qkvp1, LATENT, kc1_w, kc1_b, pk, KVD);
    // 6. conv2 as split-K bf16 GEMMs; partials merged inside qk_final
    gemm_bf16<1><<<dim3(LATENT / 128, BS / 128, 2), 256, 0, stream>>>(pq, qc2wr, nullptr, qc2, BS, LATENT, LATENT * 3, LATENT, LATENT * 3 / 2, QC2_PS);
    gemm_bf16<1><<<dim3(KVD / 128, BS / 128, 2), 256, 0, stream>>>(pk, kc2wr, nullptr, kc2, BS, KVD, KVD * 3, KVD, KVD * 3 / 2, KC2_PS);
    // 7. fused merge+bias, +0.5*mean, l2norm, rope
    qk_final<<<dim3(BS, NH + NKV), 64, 0, stream>>>(qc2, qc2p1, kc2, kc2p1, qc2_b, kc2_b,
                                                    qmean, kmean, key_temp, rtab, qTb, kTb);
    // 8. attention, key-split x2 (1024 blocks, 4/CU, balanced 34 phases/CU) + merge
    attn_mfma<<<dim3(1024), 256, 0, stream>>>(qTb, kTb, vTb, apnum, apden);
    attn_merge<<<dim3(2048), 256, 0, stream>>>(apnum, apden, attnb);
    // 9. output projection (1024 blocks, 4/CU) -- overwrites all of d_out
    gemm_bf16<0><<<dim3(DIMX / 128, BS / 128, 1), 256, 0, stream>>>(attnb, wob, nullptr, outp, BS, DIMX, LATENT, 0, LATENT, 0);
}

// Round 15
// 338.488 us; speedup vs baseline: 1.1725x; 1.0528x over previous
//
#include <hip/hip_runtime.h>
#include <hip/hip_bf16.h>
#include <cstddef>

#define NB 2
#define SEQ 2048
#define DIMX 4096
#define NH 16
#define NKV 4
#define HD 64
#define LATENT 1024
#define KVD 256
#define QKVN 1536
#define BS (NB*SEQ)
#define SP (SEQ+2)   // padded token rows per batch for conv2 input

typedef __attribute__((ext_vector_type(8))) short short8v;   // 8 bf16 = 4 VGPR
typedef __attribute__((ext_vector_type(4))) float f32x4;
typedef __attribute__((ext_vector_type(4))) unsigned short ushort4v;
typedef __attribute__((ext_vector_type(4))) unsigned int uint4v;

static __device__ __forceinline__ unsigned short f2bf(float f) {
    union { float f; unsigned u; } v; v.f = f;
    unsigned r = v.u + 0x7fffu + ((v.u >> 16) & 1u);
    return (unsigned short)(r >> 16);
}

static __device__ __forceinline__ unsigned cvt_pk_bf16(float lo, float hi) {
    unsigned r;
    asm("v_cvt_pk_bf16_f32 %0, %1, %2" : "=v"(r) : "v"(lo), "v"(hi));
    return r;
}

static __device__ __forceinline__ void gload_lds16(const unsigned short* g, unsigned short* l) {
    __builtin_amdgcn_global_load_lds((const __attribute__((address_space(1))) void*)g,
                                     (__attribute__((address_space(3))) void*)l, 16, 0, 0);
}

// ---------------- fused fp32 -> bf16 casts for x and w_qkv ----------------
#define XC_BLK (BS*DIMX/4/256)        // 16384
#define WC_BLK (QKVN*DIMX/4/256)      // 6144
__global__ __launch_bounds__(256)
void cast_inputs(const float* __restrict__ x, unsigned short* __restrict__ xb,
                 const float* __restrict__ wq, unsigned short* __restrict__ wqb)
{
    const int blk = blockIdx.x;
    const float* in; unsigned short* out; int i;
    if (blk < XC_BLK) { in = x; out = xb; i = blk * 256 + threadIdx.x; }
    else              { in = wq; out = wqb; i = (blk - XC_BLK) * 256 + threadIdx.x; }
    const float4 v = *reinterpret_cast<const float4*>(in + (size_t)i * 4);
    ushort4v o = {f2bf(v.x), f2bf(v.y), f2bf(v.z), f2bf(v.w)};
    *reinterpret_cast<ushort4v*>(out + (size_t)i * 4) = o;
}

// ---------------- fused prep: w_o cast | qc2w reorder | kc2w reorder | rope table | zero pads ----------------
#define WO_BLK 4096    // DIMX*LATENT/4/256
#define QW_N (LATENT*LATENT*3)
#define QW_BLK 12288
#define KW_N (KVD*KVD*3)
#define KW_BLK 768
#define RT_BLK 256     // SEQ*32/256
__global__ __launch_bounds__(256)
void prep_misc(const float* __restrict__ wo, unsigned short* __restrict__ wob,
               const float* __restrict__ qc2w, unsigned short* __restrict__ qc2wr,
               const float* __restrict__ kc2w, unsigned short* __restrict__ kc2wr,
               float2* __restrict__ rtab,
               unsigned short* __restrict__ pq, unsigned short* __restrict__ pk)
{
    const int blk = blockIdx.x, tid = threadIdx.x;
    if (blk < WO_BLK) {
        const int i = blk * 256 + tid;
        const float4 v = *reinterpret_cast<const float4*>(wo + (size_t)i * 4);
        ushort4v o = {f2bf(v.x), f2bf(v.y), f2bf(v.z), f2bf(v.w)};
        *reinterpret_cast<ushort4v*>(wob + (size_t)i * 4) = o;
    } else if (blk < WO_BLK + QW_BLK) {
        const int idx = (blk - WO_BLK) * 256 + tid;
        if (idx < QW_N) {
            const int o = idx / (LATENT * 3), rem = idx % (LATENT * 3);
            const int j = rem / LATENT, c = rem % LATENT;
            qc2wr[idx] = f2bf(qc2w[(size_t)o * LATENT * 3 + c * 3 + j]);
        }
    } else if (blk < WO_BLK + QW_BLK + KW_BLK) {
        const int idx = (blk - WO_BLK - QW_BLK) * 256 + tid;
        if (idx < KW_N) {
            const int o = idx / (KVD * 3), rem = idx % (KVD * 3);
            const int j = rem / KVD, c = rem % KVD;
            kc2wr[idx] = f2bf(kc2w[(size_t)o * KVD * 3 + c * 3 + j]);
        }
    } else if (blk < WO_BLK + QW_BLK + KW_BLK + RT_BLK) {
        const int idx = (blk - WO_BLK - QW_BLK - KW_BLK) * 256 + tid;
        const int s = idx >> 5, i = idx & 31;
        const float inv = powf(10000.f, -(float)(2 * i) * (1.f / HD));
        const float ang = (float)s * inv;
        rtab[idx] = make_float2(cosf(ang), sinf(ang));
    } else {
        const int t = (blk - WO_BLK - QW_BLK - KW_BLK - RT_BLK) * 256 + tid;
        if (t < 2 * 2 * LATENT) {
            const int b = t / (2 * LATENT), r = (t % (2 * LATENT)) / LATENT, c = t % LATENT;
            pq[((size_t)b * SP + r) * LATENT + c] = 0;
        }
        if (t < 2 * 2 * KVD) {
            const int b = t / (2 * KVD), r = (t % (2 * KVD)) / KVD, c = t % KVD;
            pk[((size_t)b * SP + r) * KVD + c] = 0;
        }
    }
}

// ---------------- bf16 MFMA GEMM: C[M][N] = A[M][K] @ W[N][K]^T, fp32 out ----------------
// 128x128 tile, BK=32, 2-phase double-buffered global_load_lds staging, split-K via grid.z.
// Partial base: z==0 -> C, z==1 -> C+ps1, z==2 -> C+ps2.
template<int CONV>
__global__ __launch_bounds__(256)
void gemm_bf16(const unsigned short* __restrict__ A, const unsigned short* __restrict__ W,
               const float* __restrict__ bias, float* __restrict__ C,
               int M, int N, int K, int Cch, int klen, size_t ps1, size_t ps2)
{
    __shared__ unsigned short Abuf[2][128 * 32];
    __shared__ unsigned short Bbuf[2][128 * 32];
    const int gx = gridDim.x;
    const int nwg = gx * gridDim.y;
    const int lin = blockIdx.y * gx + blockIdx.x;
    const int swz = (lin & 7) * (nwg >> 3) + (lin >> 3);
    const int n0 = (swz % gx) * 128, m0 = (swz / gx) * 128;
    const int koff = blockIdx.z * klen;
    C += (blockIdx.z == 1) ? ps1 : (blockIdx.z == 2 ? ps2 : 0);
    const int tid = threadIdx.x;
    const int wave = tid >> 6, lane = tid & 63;
    const int lg = lane >> 4, lr = lane & 15;
    const int wm = (wave & 1) * 64, wn = (wave >> 1) * 64;
    const int sr = wave * 32 + (lane >> 2);
    const int sc = (lane & 3) * 8;
    const int bb = m0 / SEQ, s0 = m0 % SEQ;

    const int NT = klen / 32;
    f32x4 acc[4][4];
    #pragma unroll
    for (int i = 0; i < 4; i++)
        #pragma unroll
        for (int j = 0; j < 4; j++) acc[i][j] = (f32x4){0.f, 0.f, 0.f, 0.f};

    auto stage = [&](int buf, int kt) {
        const int k0 = koff + kt * 32;
        const unsigned short* ga0;
        if (!CONV) {
            ga0 = A + (size_t)(m0 + sr) * K + k0 + sc;
        } else {
            const int j = k0 / Cch, c0 = k0 - j * Cch;
            ga0 = A + (size_t)(bb * SP + s0 + j + sr) * Cch + c0 + sc;
        }
        const unsigned short* gb0 = W + (size_t)(n0 + sr) * K + k0 + sc;
        const size_t astep = (size_t)16 * (CONV ? Cch : K);
        #pragma unroll
        for (int i = 0; i < 2; i++) {
            gload_lds16(ga0 + i * astep, &Abuf[buf][(wave * 2 + i) * 512]);
            gload_lds16(gb0 + (size_t)i * 16 * K, &Bbuf[buf][(wave * 2 + i) * 512]);
        }
    };

    stage(0, 0);
    __syncthreads();
    int cur = 0;
    for (int kt = 0; kt < NT; ++kt) {
        if (kt + 1 < NT) stage(cur ^ 1, kt + 1);
        short8v af[4], bf[4];
        #pragma unroll
        for (int mi = 0; mi < 4; mi++)
            af[mi] = *reinterpret_cast<const short8v*>(&Abuf[cur][(wm + mi * 16 + lr) * 32 + lg * 8]);
        #pragma unroll
        for (int ni = 0; ni < 4; ni++)
            bf[ni] = *reinterpret_cast<const short8v*>(&Bbuf[cur][(wn + ni * 16 + lr) * 32 + lg * 8]);
        #pragma unroll
        for (int mi = 0; mi < 4; mi++)
            #pragma unroll
            for (int ni = 0; ni < 4; ni++)
                acc[mi][ni] = __builtin_amdgcn_mfma_f32_16x16x32_bf16(af[mi], bf[ni], acc[mi][ni], 0, 0, 0);
        __syncthreads();
        cur ^= 1;
    }

    #pragma unroll
    for (int ni = 0; ni < 4; ni++) {
        const int col = n0 + wn + ni * 16 + lr;
        const float bv = bias ? bias[col] : 0.f;
        #pragma unroll
        for (int mi = 0; mi < 4; mi++)
            #pragma unroll
            for (int r = 0; r < 4; r++)
                C[(size_t)(m0 + wm + mi * 16 + lg * 4 + r) * N + col] = acc[mi][ni][r] + bv;
    }
}

// ---------------- fused grouped causal conv1 q+k (reads qkv split-K partials p0+p1) ----------------
// grid.z: 0..15 = q groups, 16..19 = k groups
__global__ __launch_bounds__(256)
void conv1_grouped(const float* __restrict__ qkv0, const float* __restrict__ qkv1,
                   const float* __restrict__ qw, const float* __restrict__ qb,
                   const float* __restrict__ kw, const float* __restrict__ kb,
                   unsigned short* __restrict__ pq, unsigned short* __restrict__ pk)
{
    const int t0 = blockIdx.x * 64;
    const int b  = blockIdx.y;
    const int z  = blockIdx.z;
    const bool isq = (z < NH);
    const int g  = isq ? z : z - NH;
    const int coloff = isq ? 0 : LATENT;
    const float* w = isq ? qw : kw;
    const float* bias = isq ? qb : kb;
    unsigned short* out = isq ? pq : pk;
    const int CH = isq ? LATENT : KVD;

    __shared__ float xs[66][64];
    for (int idx = threadIdx.x; idx < 66 * 64; idx += 256) {
        const int i = idx >> 6, ic = idx & 63;
        const int tt = t0 + i - 2;
        float v = 0.f;
        if (tt >= 0) {
            const size_t off = (size_t)(b * SEQ + tt) * QKVN + coloff + g * 64 + ic;
            v = qkv0[off] + qkv1[off];
        }
        xs[i][ic] = v;
    }
    __syncthreads();
    const int oc = threadIdx.x & 63;
    const int ibase = (threadIdx.x >> 6) * 16;
    float acc[16];
    const float bv = bias[g * 64 + oc];
    #pragma unroll
    for (int i = 0; i < 16; i++) acc[i] = bv;
    const float* wp = w + (size_t)(g * 64 + oc) * 192;
    for (int ic = 0; ic < 64; ic++) {
        const float w0 = wp[ic * 3 + 0], w1 = wp[ic * 3 + 1], w2 = wp[ic * 3 + 2];
        float xv[18];
        #pragma unroll
        for (int r = 0; r < 18; r++) xv[r] = xs[ibase + r][ic];
        #pragma unroll
        for (int i = 0; i < 16; i++) acc[i] += w0 * xv[i] + w1 * xv[i + 1] + w2 * xv[i + 2];
    }
    #pragma unroll
    for (int i = 0; i < 16; i++)
        out[((size_t)b * SP + 2 + t0 + ibase + i) * CH + g * 64 + oc] = f2bf(acc[i]);
}

// ---------------- head means + shifted-v build (reads qkv partials p0+p1) ----------------
__global__ __launch_bounds__(64)
void meanv_kernel(const float* __restrict__ qkv0, const float* __restrict__ qkv1,
                  float* __restrict__ qmean, float* __restrict__ kmean,
                  unsigned short* __restrict__ vRow)
{
    const int t = blockIdx.x, d = threadIdx.x;
    const int b = t >> 11, s = t & (SEQ - 1);
    const float* r0 = qkv0 + (size_t)t * QKVN;
    const float* r1 = qkv1 + (size_t)t * QKVN;
    float qs = 0.f;
    #pragma unroll
    for (int h = 0; h < NH; h++) qs += r0[h * 64 + d] + r1[h * 64 + d];
    qmean[t * 64 + d] = qs * (1.f / NH);
    float ks = 0.f;
    #pragma unroll
    for (int h = 0; h < NKV; h++) ks += r0[LATENT + h * 64 + d] + r1[LATENT + h * 64 + d];
    kmean[t * 64 + d] = ks * (1.f / NKV);
    #pragma unroll
    for (int g = 0; g < NKV; g++) {
        const int c = g * 64 + d;
        float v;
        if (c < 128) {
            v = r0[LATENT + KVD + c] + r1[LATENT + KVD + c];
        } else {
            v = 0.f;
            if (s > 0) {
                const size_t off = (size_t)(t - 1) * QKVN + LATENT + KVD + 128 + (c - 128);
                v = qkv0[off] + qkv1[off];
            }
        }
        vRow[((size_t)(b * NKV + g) * SEQ + s) * 64 + d] = f2bf(v);
    }
}

// ---------------- V transpose to d-major: vTb[bg][d][S] ----------------
__global__ __launch_bounds__(256)
void vtrans(const unsigned short* __restrict__ vRow, unsigned short* __restrict__ vTb)
{
    const int s0 = blockIdx.x * 64;
    const int bg = blockIdx.y;
    __shared__ unsigned short t[64][72];
    const int tid = threadIdx.x;
    {
        const int r = tid >> 2, c0 = (tid & 3) * 16;
        const unsigned short* p = vRow + ((size_t)bg * SEQ + s0 + r) * 64 + c0;
        const short8v a = *reinterpret_cast<const short8v*>(p);
        const short8v bv = *reinterpret_cast<const short8v*>(p + 8);
        #pragma unroll
        for (int j = 0; j < 8; j++) { t[r][c0 + j] = (unsigned short)a[j]; t[r][c0 + 8 + j] = (unsigned short)bv[j]; }
    }
    __syncthreads();
    {
        const int d = tid >> 2, ss = (tid & 3) * 16;
        short8v o0, o1;
        #pragma unroll
        for (int j = 0; j < 8; j++) { o0[j] = (short)t[ss + j][d]; o1[j] = (short)t[ss + 8 + j][d]; }
        unsigned short* op = vTb + ((size_t)bg * 64 + d) * SEQ + s0 + ss;
        *reinterpret_cast<short8v*>(op) = o0;
        *reinterpret_cast<short8v*>(op + 8) = o1;
    }
}

// ---------------- fused conv2-partial merge (3q/2k) + bias, +0.5*mean, l2norm, rope -> bf16 ----------------
__global__ __launch_bounds__(64)
void qk_final(const float* __restrict__ qc2a, const float* __restrict__ qc2b, const float* __restrict__ qc2c,
              const float* __restrict__ kc2a, const float* __restrict__ kc2b,
              const float* __restrict__ qbias, const float* __restrict__ kbias,
              const float* __restrict__ qmean, const float* __restrict__ kmean,
              const float* __restrict__ key_temp, const float2* __restrict__ rtab,
              unsigned short* __restrict__ qTb, unsigned short* __restrict__ kTb)
{
    const int t = blockIdx.x, hh = blockIdx.y, d = threadIdx.x;
    const int b = t >> 11, s = t & (SEQ - 1);
    float val;
    if (hh < NH) {
        const size_t off = (size_t)t * LATENT + hh * 64 + d;
        val = qc2a[off] + qc2b[off] + qc2c[off] + qbias[hh * 64 + d] + 0.5f * kmean[t * 64 + d];
    } else {
        const size_t off = (size_t)t * KVD + (hh - NH) * 64 + d;
        val = kc2a[off] + kc2b[off] + kbias[(hh - NH) * 64 + d] + 0.5f * qmean[t * 64 + d];
    }
    float ss = val * val;
    #pragma unroll
    for (int off = 32; off >= 1; off >>= 1) ss += __shfl_xor(ss, off);
    const float n = sqrtf(ss);
    val = val / fmaxf(n, 1e-12f);
    if (hh >= NH) val *= key_temp[0];
    const float2 cs = rtab[s * 32 + (d >> 1)];
    const float cv = cs.x, sv = cs.y;
    const float partner = __shfl_xor(val, 1);
    const float x1 = (d & 1) ? partner : val;
    const float x2 = (d & 1) ? val : partner;
    const float o = (d & 1) ? (x1 * sv + x2 * cv) : (x1 * cv - x2 * sv);
    if (hh < NH) qTb[((size_t)(b * NH + hh) * SEQ + s) * 64 + d] = f2bf(o);
    else         kTb[((size_t)(b * NKV + (hh - NH)) * SEQ + s) * 64 + d] = f2bf(o);
}

// ---------------- MFMA causal GQA attention: key-split x2, 4-wave shared staging, BK=64 ----------------
__global__ __launch_bounds__(256)
void attn_mfma(const unsigned short* __restrict__ qTb, const unsigned short* __restrict__ kTb,
               const unsigned short* __restrict__ vTb,
               unsigned short* __restrict__ pnum, float* __restrict__ pden)
{
    const int wg = blockIdx.x;
    const int qg = wg >> 8;             // quartile 0..3
    const int u = wg & 255;
    const int xcd = u & 7, i = u >> 3;
    const int bh = (xcd << 2) | (i >> 3);
    const int r = i & 7;
    const int p = (qg == 0) ? r : (qg == 1) ? (15 - r) : (qg == 2) ? (16 + r) : (31 - r);
    const int blk = 15 - (p >> 1);
    const int part = p & 1;
    const int half = blk + 1;           // phases per part
    const int cbeg = part * half, cend = cbeg + half;

    const int b = bh >> 4, h = bh & 15, g = h >> 2;
    const int tid = threadIdx.x;
    const int wave = tid >> 6, lane = tid & 63;
    const int lg = lane >> 4, lr = lane & 15;
    const int qt = blk * 4 + wave;
    const int q0 = qt * 32;

    __shared__ __align__(16) unsigned short SB[2][16][512];

    short8v qf[2][2];
    const unsigned short* qbase = qTb + ((size_t)(b * NH + h) * SEQ + q0) * 64;
    #pragma unroll
    for (int mf = 0; mf < 2; mf++)
        #pragma unroll
        for (int dc = 0; dc < 2; dc++)
            qf[mf][dc] = *reinterpret_cast<const short8v*>(qbase + (size_t)(mf * 16 + lr) * 64 + dc * 32 + lg * 8);

    f32x4 acc[2][4];
    float lsum[2] = {0.f, 0.f};
    #pragma unroll
    for (int mf = 0; mf < 2; mf++)
        #pragma unroll
        for (int dt = 0; dt < 4; dt++) acc[mf][dt] = (f32x4){0.f, 0.f, 0.f, 0.f};

    const unsigned short* kbase = kTb + (size_t)(b * NKV + g) * SEQ * 64;
    const unsigned short* vbase = vTb + (size_t)(b * NKV + g) * 64 * SEQ;
    const float EC = 0.125f * 1.44269504f;
    const int src01 = ((lg & 1) << 5) + lr;
    const int src23 = src01 + 16;
    const bool hi = (lg >= 2);

    auto stage64 = [&](int buf, int cc) {
        const int kb = cc * 64;
        #pragma unroll
        for (int i2 = 0; i2 < 4; i2++) {
            const int ch = wave * 4 + i2;
            const int st = ch >> 3, chl = ch & 7;
            const int k0 = kb + st * 32;
            const unsigned short* src;
            if (chl < 4) src = kbase + (size_t)(k0 + (chl >> 1) * 16 + lr) * 64 + (chl & 1) * 32 + lg * 8;
            else         src = vbase + (size_t)((chl - 4) * 16 + lr) * SEQ + k0 + lg * 8;
            gload_lds16(src, &SB[buf][ch][lane * 8]);
        }
    };

    stage64(0, cbeg);
    __syncthreads();
    int cur = 0;
    for (int cc = cbeg; cc < cend; ++cc) {
        if (cc + 1 < cend) stage64(cur ^ 1, cc + 1);
        #pragma unroll
        for (int st = 0; st < 2; ++st) {
            const int c = cc * 2 + st;
            if (c > qt) continue;
            const int k0 = c * 32;
            short8v kf[2][2], vf[4];
            #pragma unroll
            for (int kt = 0; kt < 2; kt++)
                #pragma unroll
                for (int dc = 0; dc < 2; dc++)
                    kf[kt][dc] = *reinterpret_cast<const short8v*>(&SB[cur][st * 8 + kt * 2 + dc][lane * 8]);
            #pragma unroll
            for (int dt = 0; dt < 4; dt++)
                vf[dt] = *reinterpret_cast<const short8v*>(&SB[cur][st * 8 + 4 + dt][lane * 8]);

            const bool diag = (c == qt);
            #pragma unroll
            for (int mf = 0; mf < 2; mf++) {
                f32x4 z0 = (f32x4){0.f, 0.f, 0.f, 0.f}, z1 = (f32x4){0.f, 0.f, 0.f, 0.f};
                __builtin_amdgcn_s_setprio(1);
                z0 = __builtin_amdgcn_mfma_f32_16x16x32_bf16(kf[0][0], qf[mf][0], z0, 0, 0, 0);
                z0 = __builtin_amdgcn_mfma_f32_16x16x32_bf16(kf[0][1], qf[mf][1], z0, 0, 0, 0);
                z1 = __builtin_amdgcn_mfma_f32_16x16x32_bf16(kf[1][0], qf[mf][0], z1, 0, 0, 0);
                z1 = __builtin_amdgcn_mfma_f32_16x16x32_bf16(kf[1][1], qf[mf][1], z1, 0, 0, 0);
                __builtin_amdgcn_s_setprio(0);
                float p0[4], p1[4];
                #pragma unroll
                for (int rr = 0; rr < 4; rr++) {
                    p0[rr] = exp2f(z0[rr] * EC);
                    p1[rr] = exp2f(z1[rr] * EC);
                }
                if (diag) {
                    const int q = q0 + mf * 16 + lr;
                    #pragma unroll
                    for (int rr = 0; rr < 4; rr++) {
                        if (k0 + 4 * lg + rr > q)      p0[rr] = 0.f;
                        if (k0 + 16 + 4 * lg + rr > q) p1[rr] = 0.f;
                    }
                }
                lsum[mf] += (p0[0] + p0[1]) + (p0[2] + p0[3]) + (p1[0] + p1[1]) + (p1[2] + p1[3]);
                const unsigned W00 = cvt_pk_bf16(p0[0], p0[1]);
                const unsigned W01 = cvt_pk_bf16(p0[2], p0[3]);
                const unsigned W10 = cvt_pk_bf16(p1[0], p1[1]);
                const unsigned W11 = cvt_pk_bf16(p1[2], p1[3]);
                const unsigned a0 = __shfl(W00, src01), b0 = __shfl(W10, src01);
                const unsigned a1 = __shfl(W01, src01), b1 = __shfl(W11, src01);
                const unsigned a2 = __shfl(W00, src23), b2 = __shfl(W10, src23);
                const unsigned a3 = __shfl(W01, src23), b3 = __shfl(W11, src23);
                uint4v pw;
                pw.x = hi ? b0 : a0;
                pw.y = hi ? b1 : a1;
                pw.z = hi ? b2 : a2;
                pw.w = hi ? b3 : a3;
                const short8v pa = __builtin_bit_cast(short8v, pw);
                __builtin_amdgcn_s_setprio(1);
                #pragma unroll
                for (int dt = 0; dt < 4; dt++)
                    acc[mf][dt] = __builtin_amdgcn_mfma_f32_16x16x32_bf16(pa, vf[dt], acc[mf][dt], 0, 0, 0);
                __builtin_amdgcn_s_setprio(0);
            }
        }
        __syncthreads();
        cur ^= 1;
    }

    float den[2];
    #pragma unroll
    for (int mf = 0; mf < 2; mf++) {
        float s = lsum[mf];
        s += __shfl_xor(s, 16); s += __shfl_xor(s, 32);
        den[mf] = s;
    }

    const int base = ((bh * 64 + qt) * 2 + part);
    if (lg == 0) {
        pden[base * 32 + lr] = den[0];
        pden[base * 32 + 16 + lr] = den[1];
    }
    unsigned short* np = pnum + (size_t)base * 2048;
    #pragma unroll
    for (int mf = 0; mf < 2; mf++)
        #pragma unroll
        for (int dt = 0; dt < 4; dt++)
            #pragma unroll
            for (int rr = 0; rr < 4; rr++)
                np[(mf * 16 + 4 * lg + rr) * 64 + dt * 16 + lr] = f2bf(acc[mf][dt][rr]);
}

// ---------------- merge key-split partials -> bf16 attn output ----------------
__global__ __launch_bounds__(256)
void attn_merge(const unsigned short* __restrict__ pnum, const float* __restrict__ pden,
                unsigned short* __restrict__ attnb)
{
    const int idx = blockIdx.x * 256 + threadIdx.x;   // 524288
    const int d0 = (idx & 7) * 8;
    const int qr = (idx >> 3) & 31;
    const int qt = (idx >> 8) & 63;
    const int bh = idx >> 14;
    const int base = (bh * 64 + qt) * 2;
    const float den = pden[base * 32 + qr] + pden[(base + 1) * 32 + qr];
    const float inv = 1.f / den;
    const short8v n0 = *reinterpret_cast<const short8v*>(pnum + (size_t)base * 2048 + qr * 64 + d0);
    const short8v n1 = *reinterpret_cast<const short8v*>(pnum + (size_t)(base + 1) * 2048 + qr * 64 + d0);
    short8v ov;
    #pragma unroll
    for (int j = 0; j < 8; j++) {
        union { unsigned u; float f; } t0, t1;
        t0.u = ((unsigned)(unsigned short)n0[j]) << 16;
        t1.u = ((unsigned)(unsigned short)n1[j]) << 16;
        ov[j] = (short)f2bf((t0.f + t1.f) * inv);
    }
    const int q = qt * 32 + qr;
    const int b = bh >> 4, h = bh & 15;
    *reinterpret_cast<short8v*>(attnb + (size_t)(b * SEQ + q) * LATENT + h * 64 + d0) = ov;
}

extern "C" void kernel_launch(void* const* d_in, const int* in_sizes, int n_in,
                              void* d_out, int out_size, void* d_ws, size_t ws_size,
                              hipStream_t stream)
{
    const float* x       = (const float*)d_in[0];
    const float* w_qkv   = (const float*)d_in[1];
    const float* w_o     = (const float*)d_in[2];
    const float* qc1_w   = (const float*)d_in[3];
    const float* qc1_b   = (const float*)d_in[4];
    const float* qc2_w   = (const float*)d_in[5];
    const float* qc2_b   = (const float*)d_in[6];
    const float* kc1_w   = (const float*)d_in[7];
    const float* kc1_b   = (const float*)d_in[8];
    const float* kc2_w   = (const float*)d_in[9];
    const float* kc2_b   = (const float*)d_in[10];
    const float* key_temp = (const float*)d_in[11];

    // --- workspace layout (aliased by lifetime; byte offsets noted) ---
    char* wsb = (char*)d_ws;
    float* qkv = (float*)wsb;                 wsb += (size_t)BS * QKVN * 4;     // [0, 25165824)
    float* qc2 = qkv;                                                            // alias (qkv dead after conv1)
    float* kc2 = (float*)((char*)qkv + (size_t)BS * LATENT * 4);                 // [16777216, 20971520)
    unsigned short* pq  = (unsigned short*)wsb;  wsb += (size_t)NB * SP * LATENT * 2;  // [25165824, 33562624)
    unsigned short* pk  = (unsigned short*)wsb;  wsb += (size_t)NB * SP * KVD * 2;     // [33562624, 35661824)
    float* qmean = (float*)wsb;  wsb += (size_t)BS * HD * 4;
    float* kmean = (float*)wsb;  wsb += (size_t)BS * HD * 4;
    unsigned short* qTb  = (unsigned short*)wsb;  wsb += (size_t)BS * LATENT * 2;
    unsigned short* kTb  = (unsigned short*)wsb;  wsb += (size_t)BS * KVD * 2;
    unsigned short* vRow = (unsigned short*)wsb;  wsb += (size_t)BS * KVD * 2;
    unsigned short* vTb  = (unsigned short*)wsb;  wsb += (size_t)BS * KVD * 2;   // ends 52439040
    unsigned short* xb   = (unsigned short*)wsb;  wsb += (size_t)BS * DIMX * 2;  // [52439040, 85993472)
    unsigned short* attnb  = xb;
    unsigned short* qc2wr  = (unsigned short*)((char*)xb + (size_t)BS * LATENT * 2);
    unsigned short* kc2wr  = (unsigned short*)((char*)qc2wr + (size_t)LATENT * LATENT * 3 * 2);
    unsigned short* wqkvb = (unsigned short*)wsb;  wsb += (size_t)QKVN * DIMX * 2;  // [85993472, 98576384)
    unsigned short* wob   = wqkvb;

    float* outp = (float*)d_out;

    // qkv split-K=2: partial z=1 in d_out (read by meanv/conv1; dead after conv1)
    float* qkvp1 = outp;
    const size_t QKV_PS = (size_t)((ptrdiff_t)(qkvp1 - qkv));
    // conv2-q split-K=3 partials: p1 = xb tail gap, p2 = d_out (free after conv1 reads)
    float* qc2p1 = (float*)((char*)d_ws + 67512320);              // [67512320, 84289536) = 16.78MB
    float* qc2p2 = outp;                                          // first 16.78MB of d_out
    const size_t QC2_PS1 = (size_t)(qc2p1 - qc2);
    const size_t QC2_PS2 = (size_t)((ptrdiff_t)(qc2p2 - qc2));
    // conv2-k split-K=2: p1 in pq region (dead after conv2-q GEMM reads pq... conv2-k GEMM runs after)
    float* kc2p1 = (float*)((char*)d_ws + (size_t)BS * QKVN * 4);
    const size_t KC2_PS1 = (size_t)(kc2p1 - kc2);
    // rope table: free gap [84289536, 85993472)
    float2* rtab = (float2*)((char*)d_ws + 84289536);             // 512KB
    // attention key-split partials: dead qc2/kc2/pq region after qk_final
    unsigned short* apnum = (unsigned short*)d_ws;                // 16.8MB  [0, 16777216)
    float* apden = (float*)((char*)d_ws + 16777216);              // 0.5MB

    // 1. fused casts for qkv GEMM
    cast_inputs<<<dim3(XC_BLK + WC_BLK), 256, 0, stream>>>(x, xb, w_qkv, wqkvb);
    // 2. qkv projection, split-K=2 (768 blocks); partials merged by consumers
    gemm_bf16<0><<<dim3(QKVN / 128, BS / 128, 2), 256, 0, stream>>>(xb, wqkvb, nullptr, qkv, BS, QKVN, DIMX, 0, DIMX / 2, QKV_PS, 0);
    // 3. fused prep (w_o cast, conv2 weight reorders, rope table, conv pads)
    prep_misc<<<dim3(WO_BLK + QW_BLK + KW_BLK + RT_BLK + 16), 256, 0, stream>>>(
        w_o, wob, qc2_w, qc2wr, kc2_w, kc2wr, rtab, pq, pk);
    // 4. means + shifted v (merging qkv partials), V transpose
    meanv_kernel<<<dim3(BS), 64, 0, stream>>>(qkv, qkvp1, qmean, kmean, vRow);
    vtrans<<<dim3(SEQ / 64, NB * NKV), 256, 0, stream>>>(vRow, vTb);
    // 5. fused grouped conv1 q+k (merging qkv partials) -> padded bf16
    conv1_grouped<<<dim3(SEQ / 64, NB, NH + NKV), 256, 0, stream>>>(qkv, qkvp1, qc1_w, qc1_b, kc1_w, kc1_b, pq, pk);
    // 6. conv2: q split-K=3 (768 blocks, p2 overwrites dead d_out), k split-K=2
    gemm_bf16<1><<<dim3(LATENT / 128, BS / 128, 3), 256, 0, stream>>>(pq, qc2wr, nullptr, qc2, BS, LATENT, LATENT * 3, LATENT, LATENT, QC2_PS1, QC2_PS2);
    gemm_bf16<1><<<dim3(KVD / 128, BS / 128, 2), 256, 0, stream>>>(pk, kc2wr, nullptr, kc2, BS, KVD, KVD * 3, KVD, KVD * 3 / 2, KC2_PS1, 0);
    // 7. fused merge (3q/2k) + bias, +0.5*mean, l2norm, rope
    qk_final<<<dim3(BS, NH + NKV), 64, 0, stream>>>(qc2, qc2p1, qc2p2, kc2, kc2p1, qc2_b, kc2_b,
                                                    qmean, kmean, key_temp, rtab, qTb, kTb);
    // 8. attention, key-split x2 (1024 blocks, 4/CU) + merge
    attn_mfma<<<dim3(1024), 256, 0, stream>>>(qTb, kTb, vTb, apnum, apden);
    attn_merge<<<dim3(2048), 256, 0, stream>>>(apnum, apden, attnb);
    // 9. output projection (1024 blocks, 4/CU) -- overwrites all of d_out
    gemm_bf16<0><<<dim3(DIMX / 128, BS / 128, 1), 256, 0, stream>>>(attnb, wob, nullptr, outp, BS, DIMX, LATENT, 0, LATENT, 0, 0);
}